// Round 13
// baseline (61.092 us; speedup 1.0000x reference)
//
#include <hip/hip_runtime.h>
#include <hip/hip_bf16.h>
#include <math.h>

// Problem constants
#define NB 256
#define LL 200
#define DD 64
#define ITEMS_N 10000
#define RANK 16
#define ALPHA 1.0001f
#define INV_ALPHA (1.0f/1.0001f)
#define INV_SQRT_HEAD 0.17677669529663687f  // 1/sqrt(32)

typedef __attribute__((ext_vector_type(8))) short short8v;
typedef __attribute__((ext_vector_type(4))) float f32x4;

static __device__ __forceinline__ unsigned short f2b(float f) {
    unsigned u = __float_as_uint(f);
    unsigned r = (u + 0x7fffu + ((u >> 16) & 1u)) >> 16;   // RNE
    return (unsigned short)r;
}
// HW packed convert: lo16 = bf16(a), hi16 = bf16(c); RNE — bit-identical to f2b
static __device__ __forceinline__ unsigned f2b2(float a, float c) {
    unsigned r;
    asm("v_cvt_pk_bf16_f32 %0, %1, %2" : "=v"(r) : "v"(a), "v"(c));
    return r;
}
static __device__ __forceinline__ float b2f(unsigned short h) {
    return __uint_as_float(((unsigned)h) << 16);
}

// LDS layout (bytes) for mega
#define OFF_A     0        // Abuf u16[208][72] : S2 (MFMA output), later Vt u16[64][232]
#define OFF_TB    29952    // Tb u16[208][232]
// scratch aliased in the head of Tb (Tb rows 0-29):
#define OFF_CL32  (OFF_TB + 0)       // f32[32][33] candidate Gram (4224 B), dead after 1bd
#define OFF_U32   (OFF_TB + 4224)    // f32[32][17] selection chol (2176 B), dead after 1bd
#define OFF_UTL   (OFF_TB + 6400)    // u16[16][232] U^T lo-part (7424 B, ends 13824),
                                     //   written 1bd, read ph.3 MFMA, dead at 4+5
// Lk tiles are written TRANSPOSED (Tb[col][row], Lk symmetric): liveness is on
// Cc: phases 1bd/3 take Cc>=2 (rows >=32), phase 4+5 takes Cc in {0,1}.
// COVERAGE: 1bd idx 0..95 (96) + ph3 idx 96..142 (47) = 143, plus 26 tiles
// Cc in {0,1} in ph.4+5 -> all 169 tile positions => Tb holds the FULL
// symmetric Lk (Tb[i][j] == Tb[j][i] bitwise, MFMA operand-swap invariant).
#define OFF_XB    (OFF_TB + 20000)   // u16[208][72] x bf16          (29952 B, ends 49952)
#define OFF_WQB   (OFF_TB + 49952)   // u16[64][72]  Wq bf16         ( 9216 B, ends 59168)
#define OFF_WVB   (OFF_TB + 59168)   // u16[64][72]  Wv bf16         ( 9216 B, ends 68384)
#define OFF_BQS   (OFF_TB + 68384)   // f32[64]
#define OFF_BVS   (OFF_TB + 68640)   // f32[64]  (scratch ends 68896 < 96512)
#define OFF_UL    126464   // Ul f32[200][16] -> later Wdb u16[64][72]
#define OFF_UB    139264   // Ub u16[208][16] (written 1bd); phase 10: per-wave halfbuf
                           //   u16[16][36] x 16 = 18,432 B (139264..157696 < dv at 160000)
#define OFF_PB    145920   // Pb u16[208][16] (written ph.7); before that hosts scratch:
#define OFF_MAUG  (OFF_PB + 0)       // f32[16][33] 2112 B (ph.3)
#define OFF_MINVT (OFF_PB + 2112)    // f32[16][20] Minv^T padded (1280 B, ph.3-5)
#define OFF_IDSL  (OFF_PB + 3392)    // int[200] (ph.0-1bd)
#define OFF_PIV   (OFF_PB + 4192)    // int[16]
#define OFF_INVSQ (OFF_PB + 4256)    // f32[16]
#define OFF_IDP   (OFF_PB + 4320)    // int[16] (ends 4384 < 6656)
#define OFF_ZB    152576   // Zb u16[16][232] (7424 B, ends 160000); 1bd->ph.3 hosts
                           //   U^T hi-part (alias); Z written 4+5. 232-stride (464 B
                           //   rows) makes fr-strided b128 reads 2-way bank-free.
#define OFF_UTH   OFF_ZB
#define OFF_DV    160000   // dv f32[208] (832 B)
#define OFF_RED   160832   // red f32[32]
#define OFF_SCAL  160960   // scal f32[4]
#define OFF_ZPAD  160976   // 64 B zeros
#define LDS_TOTAL 161040

// ---------------------------------------------------------------------------
// K_mega. R13 = R12 +:
//  - mask pass-2 prefetch hoisted to ph.8+9 top (with pass-1): its HBM drain
//    overlaps the 8+9 MFMA block; ph.10 loads only pass-3 (waves 0-1, tiny).
//    42 mask VGPRs live across ONE barrier (well under R4's 56/4-barrier fail).
//  - Z = U*Minv loop with explicit float4 LDS reads (4xb128 + 4xb128),
//    fmaf chain in ascending-k order — bit-identical.
// grid B, block 1024 (16 waves), dynamic LDS 161,040 B (1 block/CU).
// NOTE: s_setprio is permanently shelved (R9 NaN).
// ---------------------------------------------------------------------------
__global__ __launch_bounds__(1024) void mega_kernel(
        const float* __restrict__ x,    const float* __restrict__ mask,
        const int*   __restrict__ ids,  const float* __restrict__ C,
        const float* __restrict__ Wq,   const float* __restrict__ bq,
        const float* __restrict__ Wv,   const float* __restrict__ bv,
        const float* __restrict__ Wd,   const float* __restrict__ bd,
        const float* __restrict__ gamma,const float* __restrict__ beta,
        unsigned short* __restrict__ Vg, float* __restrict__ out) {
    extern __shared__ char smem[];
    unsigned short* Abuf = (unsigned short*)(smem + OFF_A);   // S2 then Vt
    unsigned short* Tb   = (unsigned short*)(smem + OFF_TB);
    float* Cl32  = (float*)(smem + OFF_CL32);
    float* U32l  = (float*)(smem + OFF_U32);
    unsigned short* xbu  = (unsigned short*)(smem + OFF_XB);
    unsigned short* Wqbu = (unsigned short*)(smem + OFF_WQB);
    unsigned short* Wvbu = (unsigned short*)(smem + OFF_WVB);
    float* bqs   = (float*)(smem + OFF_BQS);
    float* bvs   = (float*)(smem + OFF_BVS);
    float*          Ul   = (float*)(smem + OFF_UL);
    unsigned short* Wdb  = (unsigned short*)(smem + OFF_UL);  // alias (Ul dead)
    unsigned short* Ub   = (unsigned short*)(smem + OFF_UB);
    unsigned short* Pb   = (unsigned short*)(smem + OFF_PB);
    unsigned short* Zb   = (unsigned short*)(smem + OFF_ZB);
    float* dv   = (float*)(smem + OFF_DV);
    float* red  = (float*)(smem + OFF_RED);
    float* scal = (float*)(smem + OFF_SCAL);
    const short8v* zpad = (const short8v*)(smem + OFF_ZPAD);
    int*   idsl  = (int*)(smem + OFF_IDSL);
    int*   pivots= (int*)(smem + OFF_PIV);
    float* invsqv= (float*)(smem + OFF_INVSQ);
    int*   idpv  = (int*)(smem + OFF_IDP);
    float* Maug  = (float*)(smem + OFF_MAUG);
    float* MinvT = (float*)(smem + OFF_MINVT);

    int t = threadIdx.x;
    int b = blockIdx.x;
    int wv_ = t >> 6, lane = t & 63, fr = lane & 15, g = lane >> 4;

    // ---- -1) early Gram-gather issue (hides scattered-HBM latency under 0) ----
    int ga_ = t >> 5, gc_ = t & 31;
    float cgv;
    {
        int ia = ids[b*LL + ga_];
        int ic = ids[b*LL + gc_];
        cgv = C[(size_t)ia*ITEMS_N + ic];
    }

    // ---- 0) stage ids, x->bf16, Wq/Wv->bf16, biases; zero pads ----
    {
        float4 z4; z4.x = 0.f; z4.y = 0.f; z4.z = 0.f; z4.w = 0.f;
        // Tb rows 200-207 (3,712 B)
        float4* tz = (float4*)(smem + OFF_TB + 92800);
        for (int i = t; i < 232; i += 1024) tz[i] = z4;
        // Zb full region (also zero-pads U^T hi cols 200-231 for ph.3/7 MFMA)
        float4* zz = (float4*)Zb;
        for (int i = t; i < 464; i += 1024) zz[i] = z4;
        if (t < 4) ((float4*)(smem + OFF_ZPAD))[t] = z4;
        if (t < 64)  ((unsigned*)(smem + OFF_UB + 6400))[t] = 0;   // Ub rows 200-207
        // U^T-lo pad cols 200-223 (192 words; region untouched until 1bd writes)
        if (t < 192) {
            int s = t / 12, c2 = t - s*12;
            *(unsigned*)(smem + OFF_UTL + s*464 + 400 + c2*4) = 0;
        }
        // xb pad rows 200-207 (1,152 B)
        for (int i = t; i < 288; i += 1024) ((unsigned*)(smem + OFF_XB + 28800))[i] = 0;
        // x -> bf16 (float4-vectorized, packed cvt)
        const float4* x4p = (const float4*)(x + (size_t)b*12800);
        #pragma unroll
        for (int it2 = 0; it2 < 4; ++it2) {
            int i4 = t + it2*1024;
            if (i4 < 3200) {
                float4 v4 = x4p[i4];
                int r = i4 >> 4, k4 = (i4 & 15) << 2;
                *(uint2*)(xbu + r*72 + k4) =
                    make_uint2(f2b2(v4.x, v4.y), f2b2(v4.z, v4.w));
            }
        }
        // Wq/Wv -> bf16
        {
            float4 q4 = ((const float4*)Wq)[t];
            float4 w4 = ((const float4*)Wv)[t];
            int d2 = t >> 4, k4 = (t & 15) << 2;
            *(uint2*)(Wqbu + d2*72 + k4) = make_uint2(f2b2(q4.x, q4.y), f2b2(q4.z, q4.w));
            *(uint2*)(Wvbu + d2*72 + k4) = make_uint2(f2b2(w4.x, w4.y), f2b2(w4.z, w4.w));
        }
        if (t < 64) { bqs[t] = bq[t]; bvs[t] = bv[t]; }
        if (t < LL) idsl[t] = ids[b*LL + t];
        Cl32[ga_*33 + gc_] = cgv;     // gather landed during staging
    }
    __syncthreads();

    // ---- 0.5') wave 0: selection Cholesky (needs only Cl32 — ready now);
    //      waves 1-15: the 52 S2/V MFMA tiles; V held in packed regs. ----
    unsigned vpack[8];
    #pragma unroll
    for (int i = 0; i < 8; ++i) vpack[i] = 0;
    if (wv_ == 0) {
        int a = lane & 31;
        float diag = Cl32[a*33 + a] - 1.0f;
        float ur[16];
        int   mypiv = 0; float myinv = 0.f;
        bool  removed = false;
        #pragma unroll
        for (int s = 0; s < RANK; ++s) {
            float v = removed ? -3e38f : diag;
            int idx = a;
            #pragma unroll
            for (int off = 16; off > 0; off >>= 1) {
                float v2 = __shfl_xor(v, off);
                int   i2 = __shfl_xor(idx, off);
                if (v2 > v || (v2 == v && i2 < idx)) { v = v2; idx = i2; }
            }
            int p = idx; float dp = v;          // wave-uniform (p < 32)
            float iv = (dp < 1e-9f) ? 0.0f : (1.0f/sqrtf(dp));
            float c = Cl32[a*33 + p] - ((a == p) ? 1.0f : 0.0f);
            #pragma unroll
            for (int k = 0; k < s; ++k) {
                float upk = __shfl(ur[k], p);   // pivot row value U32[p][k]
                c -= ur[k] * upk;
            }
            float u = c * iv;
            ur[s] = u;
            diag -= u*u;
            if (a == p) removed = true;
            if (lane == s) { mypiv = p; myinv = iv; }
        }
        #pragma unroll
        for (int s = 0; s < RANK; ++s) U32l[a*17 + s] = ur[s];
        if (lane < 16) {
            pivots[lane] = mypiv;
            invsqv[lane] = myinv;
            idpv[lane]   = idsl[mypiv];
        }
    } else {
        #pragma unroll
        for (int it2 = 0; it2 < 4; ++it2) {
            int tile = (wv_ - 1) + 15*it2;
            if (tile < 52) {
                int R = tile >> 2, Dt = tile & 3;
                const char* ar = (const char*)smem + OFF_XB + (R*16 + fr)*144;
                const char* qr = (const char*)smem + OFF_WQB + (Dt*16 + fr)*144;
                const char* vr = (const char*)smem + OFF_WVB + (Dt*16 + fr)*144;
                short8v a0 = *(const short8v*)(ar + g*16);
                short8v a1 = *(const short8v*)(ar + 64 + g*16);
                f32x4 qa = {0.f,0.f,0.f,0.f};
                f32x4 va = {0.f,0.f,0.f,0.f};
                qa = __builtin_amdgcn_mfma_f32_16x16x32_bf16(a0, *(const short8v*)(qr + g*16), qa, 0,0,0);
                qa = __builtin_amdgcn_mfma_f32_16x16x32_bf16(a1, *(const short8v*)(qr + 64 + g*16), qa, 0,0,0);
                va = __builtin_amdgcn_mfma_f32_16x16x32_bf16(a0, *(const short8v*)(vr + g*16), va, 0,0,0);
                va = __builtin_amdgcn_mfma_f32_16x16x32_bf16(a1, *(const short8v*)(vr + 64 + g*16), va, 0,0,0);
                int col = Dt*16 + fr;
                float bqc = bqs[col], bvc = bvs[col];
                unsigned s01 = f2b2((qa[0]+bqc)*(qa[0]+bqc), (qa[1]+bqc)*(qa[1]+bqc));
                unsigned s23 = f2b2((qa[2]+bqc)*(qa[2]+bqc), (qa[3]+bqc)*(qa[3]+bqc));
                #pragma unroll
                for (int reg = 0; reg < 4; ++reg) {
                    int row = R*16 + g*4 + reg;
                    unsigned short sv = (unsigned short)
                        (((reg < 2 ? s01 : s23) >> ((reg & 1)*16)) & 0xffffu);
                    Abuf[row*72 + col] = (row < LL) ? sv : (unsigned short)0;
                }
                vpack[2*it2]     = f2b2(va[0] + bvc, va[1] + bvc);
                vpack[2*it2 + 1] = f2b2(va[2] + bvc, va[3] + bvc);
            }
        }
    }
    __syncthreads();

    // Lk tile macro: tile (R,Cc) written TRANSPOSED-PACKED to Tb[col][row0..3]
    #define LK_TILE(Ridx, Ccidx)                                               \
    {                                                                          \
        int R = (Ridx), Cc = (Ccidx);                                          \
        short8v a0 = *(const short8v*)((char*)Abuf + (R*16 + fr)*144 + g*16);  \
        short8v a1 = *(const short8v*)((char*)Abuf + (R*16 + fr)*144 + 64 + g*16); \
        short8v b0 = *(const short8v*)((char*)Abuf + (Cc*16 + fr)*144 + g*16); \
        short8v b1 = *(const short8v*)((char*)Abuf + (Cc*16 + fr)*144 + 64 + g*16); \
        f32x4 acc = {0.f, 0.f, 0.f, 0.f};                                      \
        acc = __builtin_amdgcn_mfma_f32_16x16x32_bf16(a0, b0, acc, 0, 0, 0);   \
        acc = __builtin_amdgcn_mfma_f32_16x16x32_bf16(a1, b1, acc, 0, 0, 0);   \
        int col = Cc*16 + fr, row0 = R*16 + g*4;                               \
        if (col < LL && row0 < LL) {                                           \
            *(uint2*)&Tb[col*232 + row0] =                                     \
                make_uint2(f2b2(acc[0], acc[1]), f2b2(acc[2], acc[3]));        \
        }                                                                      \
    }

    // ---- 1bd) waves 0-3: column-major pivot gather (C symmetric; 16 rows ->
    //      ~160 TLB pages) + U recursion, vectorized writes. Rows t<32 from
    //      Cl32. waves 4-15: 96 Lk tiles (idx 0..95, Cc>=2) under the gather. ----
    if (wv_ < 4) {
        if (t < LL) {
            float cg[16];
            if (t < 32) {
                #pragma unroll
                for (int s = 0; s < RANK; ++s) cg[s] = Cl32[t*33 + pivots[s]];
            } else {
                int myid = idsl[t];
                #pragma unroll
                for (int s = 0; s < RANK; ++s)
                    cg[s] = C[(size_t)idpv[s]*ITEMS_N + myid];
            }
            float ur[16];
            #pragma unroll
            for (int s = 0; s < RANK; ++s) {
                int p = pivots[s];
                float c = cg[s] - ((t == p) ? 1.0f : 0.0f);
                #pragma unroll
                for (int k = 0; k < s; ++k) c -= ur[k] * U32l[p*17 + k];
                ur[s] = c * invsqv[s];
            }
            unsigned short* Uth = (unsigned short*)(smem + OFF_UTH);
            unsigned short* Utl = (unsigned short*)(smem + OFF_UTL);
            // packed converts + vectorized Ul/Ub writes
            unsigned hp[8];
            #pragma unroll
            for (int s2 = 0; s2 < 8; ++s2) hp[s2] = f2b2(ur[2*s2], ur[2*s2 + 1]);
            float4* ul4 = (float4*)&Ul[t*RANK];
            ul4[0] = make_float4(ur[0],  ur[1],  ur[2],  ur[3]);
            ul4[1] = make_float4(ur[4],  ur[5],  ur[6],  ur[7]);
            ul4[2] = make_float4(ur[8],  ur[9],  ur[10], ur[11]);
            ul4[3] = make_float4(ur[12], ur[13], ur[14], ur[15]);
            uint4* ub4 = (uint4*)&Ub[t*RANK];
            ub4[0] = make_uint4(hp[0], hp[1], hp[2], hp[3]);
            ub4[1] = make_uint4(hp[4], hp[5], hp[6], hp[7]);
            #pragma unroll
            for (int s = 0; s < RANK; ++s) {
                unsigned short hv = (unsigned short)((hp[s >> 1] >> ((s & 1)*16)) & 0xffffu);
                Uth[s*232 + t] = hv;
                Utl[s*232 + t] = f2b(ur[s] - b2f(hv));
            }
        }
    } else {
        for (int idx = (wv_ - 4); idx < 96; idx += 12)
            LK_TILE(idx % 13, 2 + idx/13);
    }
    __syncthreads();

    // ---- 3) wave 0: M = alpha I + U^T U (split-bf16 MFMA) + 32-lane GJ
    //      (lanes 0-15 M rows, 16-31 inv rows; bit-identical arithmetic);
    //      waves 1-15: pad-zero rows 30-199 + 47 tiles (idx 96..142). ----
    if (wv_ == 0) {
        const char* uh  = smem + OFF_UTH;
        const char* ul2 = smem + OFF_UTL;
        f32x4 macc = {0.f,0.f,0.f,0.f};
        #pragma unroll
        for (int kb = 0; kb < 7; ++kb) {
            short8v h  = *(const short8v*)(uh  + fr*464 + kb*64 + g*16);
            short8v l2 = *(const short8v*)(ul2 + fr*464 + kb*64 + g*16);
            macc = __builtin_amdgcn_mfma_f32_16x16x32_bf16(h,  h,  macc, 0,0,0);
            macc = __builtin_amdgcn_mfma_f32_16x16x32_bf16(h,  l2, macc, 0,0,0);
            macc = __builtin_amdgcn_mfma_f32_16x16x32_bf16(l2, h,  macc, 0,0,0);
        }
        #pragma unroll
        for (int reg = 0; reg < 4; ++reg) {
            int r = g*4 + reg;
            Maug[r*33 + fr] = macc[reg] + ((r == fr) ? ALPHA : 0.f);
        }
        // 32-lane GJ: lanes 0-15 hold M rows, lanes 16-31 hold inverse rows
        float va[16];
        int rl = lane & 15;
        bool hi = (lane & 16) != 0;
        #pragma unroll
        for (int c = 0; c < 16; ++c)
            va[c] = hi ? ((rl == c) ? 1.0f : 0.0f) : Maug[rl*33 + c];
        #pragma unroll
        for (int s = 0; s < 16; ++s) {
            float pv = __shfl(va[s], s);          // M[s][s] (lane s, lo half)
            float f  = __shfl(va[s], rl);         // M[rl][s] (from lo lane rl)
            float pvinv = 1.0f / pv;
            int src = s + (hi ? 16 : 0);          // pivot row: M from s, inv from 16+s
            #pragma unroll
            for (int c = 0; c < 16; ++c) {
                float prow = __shfl(va[c], src) * pvinv;
                if (rl == s) va[c] = prow;
                else va[c] = fmaf(-f, prow, va[c]);
            }
        }
        if (hi && lane < 32) {
            // store TRANSPOSED, padded rows of 20 floats (16B-aligned)
            #pragma unroll
            for (int c = 0; c < 16; ++c) MinvT[c*20 + rl] = va[c];
        }
    } else {
        // Tb pad cols 200-231, rows 30-199 (above U^T-lo which ends 13824)
        for (int i = t - 64; i < 2720; i += 960) {
            int r = 30 + (i >> 4), c2 = i & 15;
            *(unsigned*)(smem + OFF_TB + r*464 + 400 + c2*4) = 0;
        }
        for (int idx = 96 + (wv_ - 1); idx < 143; idx += 15)
            LK_TILE(idx % 13, 2 + idx/13);
    }
    __syncthreads();

    // ---- 4+5) Wd reg-prefetch (T14; lands during Z/tiles, written ph.7) +
    //      Z = U*Minv -> Zb (explicit b128 reads); 26 tiles Cc=0,1; pads. ----
    float4 wd4 = ((const float4*)Wd)[t];
    for (int idx = t; idx < LL*RANK; idx += 1024) {
        int i = idx >> 4, r = idx & 15;
        const float4* u4 = (const float4*)&Ul[i*RANK];
        const float4* m4 = (const float4*)&MinvT[r*20];
        float4 ua = u4[0], ub_ = u4[1], uc = u4[2], ud = u4[3];
        float4 ma = m4[0], mb = m4[1], mc = m4[2], md = m4[3];
        float acc = 0.f;
        acc = fmaf(ua.x, ma.x, acc); acc = fmaf(ua.y, ma.y, acc);
        acc = fmaf(ua.z, ma.z, acc); acc = fmaf(ua.w, ma.w, acc);
        acc = fmaf(ub_.x, mb.x, acc); acc = fmaf(ub_.y, mb.y, acc);
        acc = fmaf(ub_.z, mb.z, acc); acc = fmaf(ub_.w, mb.w, acc);
        acc = fmaf(uc.x, mc.x, acc); acc = fmaf(uc.y, mc.y, acc);
        acc = fmaf(uc.z, mc.z, acc); acc = fmaf(uc.w, mc.w, acc);
        acc = fmaf(ud.x, md.x, acc); acc = fmaf(ud.y, md.y, acc);
        acc = fmaf(ud.z, md.z, acc); acc = fmaf(ud.w, md.w, acc);
        Zb[r*232 + i] = f2b(acc);
    }
    if (t < 480) {
        int r = t >> 4, c2 = t & 15;
        *(unsigned*)(smem + OFF_TB + r*464 + 400 + c2*4) = 0;
    }
    for (int u2 = wv_; u2 < 26; u2 += 16)
        LK_TILE(u2 % 13, u2 / 13);
    __syncthreads();            // MinvT read done; Tb holds full Lk + zero pads

    // ---- 7) mask pass-0 chunk prefetch (row wv_*4+g < 64; 14 regs) +
    //      Vt stage from held regs via packed b64 writes (S2 dead)
    //      + Wdb stage from wd4 (Ul dead; one uint2 store) + P = Lk@Z -> Pb ----
    float2 mkr0[7];
    {
        int l0 = wv_*4 + g;                       // pass-0 row, always < 64 < LL
        const float* mbase = mask + (size_t)b*40000;
        #pragma unroll
        for (int e = 0; e < 7; ++e) {
            int m0 = 2*fr + 32*e;
            mkr0[e] = (m0 < LL)
                ? *(const float2*)(mbase + (size_t)l0*200 + m0) : make_float2(0.f, 0.f);
        }
    }
    {
        unsigned short* Vt = Abuf;
        if (wv_ > 0) {
            #pragma unroll
            for (int it2 = 0; it2 < 4; ++it2) {
                int tile = (wv_ - 1) + 15*it2;
                if (tile < 52) {
                    int R = tile >> 2, Dt = tile & 3;
                    int row0 = R*16 + g*4;
                    if (row0 < LL) {   // uniform over the 4-row group (200 % 4 == 0)
                        *(uint2*)&Vt[(Dt*16 + fr)*232 + row0] =
                            make_uint2(vpack[2*it2], vpack[2*it2 + 1]);
                    }
                }
            }
        }
        for (int i = t; i < 2048; i += 1024) {
            int d = i >> 5, mc = i & 31;
            Vt[d*232 + 200 + mc] = 0;
        }
        {
            int d2 = t >> 4, k4 = (t & 15) << 2;
            *(uint2*)(Wdb + d2*72 + k4) =
                make_uint2(f2b2(wd4.x, wd4.y), f2b2(wd4.z, wd4.w));
        }
    }
    for (int strip = wv_; strip < 13; strip += 16) {
        f32x4 acc = {0.f, 0.f, 0.f, 0.f};
        const char* arow = (const char*)Tb + (size_t)(strip*16 + fr)*464;
        const char* brow = (const char*)Zb + (size_t)fr*464;
        #pragma unroll
        for (int kt = 0; kt < 7; ++kt) {
            short8v a  = *(const short8v*)(arow + kt*64 + g*16);
            short8v bb = *(const short8v*)(brow + kt*64 + g*16);
            acc = __builtin_amdgcn_mfma_f32_16x16x32_bf16(a, bb, acc, 0, 0, 0);
        }
        #pragma unroll
        for (int reg = 0; reg < 4; ++reg) {
            int prow = strip*16 + g*4 + reg;
            Pb[prow*16 + fr] = f2b(acc[reg]);
        }
    }
    __syncthreads();

    // ---- 8+9 fused, symmetric-Lk; mask pass-1 AND pass-2 prefetched here
    //      (drain overlaps the tile MFMA block; 42 mask regs over 1 barrier). ----
    float2 mkr1[7], mkr2[7];
    {
        int l1 = 64 + wv_*4 + g;                  // pass-1 row, 64..127 < LL
        int l2 = 128 + wv_*4 + g;                 // pass-2 row, 128..191 < LL
        const float* mbase = mask + (size_t)b*40000;
        #pragma unroll
        for (int e = 0; e < 7; ++e) {
            int m0 = 2*fr + 32*e;
            bool mm = (m0 < LL);
            mkr1[e] = mm ? *(const float2*)(mbase + (size_t)l1*200 + m0) : make_float2(0.f, 0.f);
            mkr2[e] = mm ? *(const float2*)(mbase + (size_t)l2*200 + m0) : make_float2(0.f, 0.f);
        }
    }
    {
        float ps = 0.f, psd = 0.f;
        for (int u = wv_; u < 91; u += 16) {
            int R, Cc;
            if (u < 13) { R = u; Cc = u; }
            else {
                int q = u - 13, rr = 0;
                while (q >= 12 - rr) { q -= 12 - rr; ++rr; }
                R = rr; Cc = rr + 1 + q;
            }
            const short8v* pPR = (g < 2) ? (const short8v*)((const char*)Pb + (R*16 + fr)*32 + g*16) : zpad;
            const short8v* pUC = (g < 2) ? (const short8v*)((const char*)Ub + (Cc*16 + fr)*32 + g*16) : zpad;
            const short8v* pUR = (g < 2) ? (const short8v*)((const char*)Ub + (R*16 + fr)*32 + g*16) : zpad;
            const short8v* pPC = (g < 2) ? (const short8v*)((const char*)Pb + (Cc*16 + fr)*32 + g*16) : zpad;
            f32x4 acc1 = {0.f,0.f,0.f,0.f};
            f32x4 acc2 = {0.f,0.f,0.f,0.f};
            acc1 = __builtin_amdgcn_mfma_f32_16x16x32_bf16(*pPR, *pUC, acc1, 0,0,0);  // (PU^T)[row][col]
            acc2 = __builtin_amdgcn_mfma_f32_16x16x32_bf16(*pUR, *pPC, acc2, 0,0,0);  // (PU^T)[col][row]
            int col = Cc*16 + fr, row0 = R*16 + g*4;
            // packed lk read from transposed (identical) position, own-tile addr
            uint2 lk2 = *(const uint2*)&Tb[col*232 + row0];
            if (u < 13) {
                #pragma unroll
                for (int reg = 0; reg < 4; ++reg) {
                    int row = row0 + reg;
                    float lk = b2f((unsigned short)
                        (((reg < 2 ? lk2.x : lk2.y) >> ((reg & 1)*16)) & 0xffffu));
                    float tvA = (lk - acc1[reg]) * INV_ALPHA;
                    float tvT = (lk - acc2[reg]) * INV_ALPHA;
                    if (row < LL && col < LL) {
                        float w = tvA * tvT;
                        Tb[row*232 + col] = f2b(w);
                        ps += w;
                        if (row == col) { dv[row] = tvA; psd += tvA; }
                    }
                }
            } else {
                // off-diagonal: rows = row0+reg <= 191 < LL always (R <= 11)
                float w[4];
                #pragma unroll
                for (int reg = 0; reg < 4; ++reg) {
                    float lk = b2f((unsigned short)
                        (((reg < 2 ? lk2.x : lk2.y) >> ((reg & 1)*16)) & 0xffffu));
                    float tvA = (lk - acc1[reg]) * INV_ALPHA;
                    float tvT = (lk - acc2[reg]) * INV_ALPHA;
                    w[reg] = tvA * tvT;
                }
                uint2 pk = make_uint2(f2b2(w[0], w[1]), f2b2(w[2], w[3]));
                if (col < LL) {
                    #pragma unroll
                    for (int reg = 0; reg < 4; ++reg) {
                        int row = row0 + reg;
                        Tb[row*232 + col] = (unsigned short)
                            (((reg < 2 ? pk.x : pk.y) >> ((reg & 1)*16)) & 0xffffu);
                        ps += 2.0f * w[reg];
                    }
                    *(uint2*)&Tb[col*232 + row0] = pk;   // W symmetric, packed b64
                }
            }
        }
        #pragma unroll
        for (int off = 32; off > 0; off >>= 1) {
            ps  += __shfl_xor(ps, off);
            psd += __shfl_xor(psd, off);
        }
        if (lane == 0) { red[wv_] = ps; red[16 + wv_] = psd; }
        __syncthreads();
        // parallel reduce: lanes 0-15 sum ps parts, 16-31 sum psd parts
        if (t < 32) {
            float v = red[t];
            v += __shfl_xor(v, 1);
            v += __shfl_xor(v, 2);
            v += __shfl_xor(v, 4);
            v += __shfl_xor(v, 8);
            float s1 = __shfl(v, 0);
            float s2 = __shfl(v, 16);
            if (t == 0) {
                float dn = fmaxf(0.5f*(s2*s2 - s1), 1e-9f);
                scal[0] = 1.0f / dn;
            }
        }
        __syncthreads();
    }

    // ---- 10) softmax: 4 passes over ALL 16 waves (row = p*64 + wv_*4 + g;
    //      passes 0-2 bound-free, pass 3 waves 0-1 only), then barrier,
    //      then PV -> proj -> LN on the 13 strip owners. ----
    {
        const unsigned short* Vt = Abuf;
        float invden = scal[0];
        // mask pass-3 only (waves 0-1; passes 0-2 already in registers)
        float2 mkr3[7];
        {
            const float* mbase = mask + (size_t)b*40000;
            int l3 = 192 + wv_*4 + g;             // valid only for wv_ < 2
            bool p3 = (wv_ < 2);
            #pragma unroll
            for (int e = 0; e < 7; ++e) {
                int m0 = 2*fr + 32*e;
                mkr3[e] = ((m0 < LL) && p3)
                    ? *(const float2*)(mbase + (size_t)l3*200 + m0) : make_float2(0.f, 0.f);
            }
        }
        // hoist dv pairs once (shared by all 4 passes)
        float2 dvv[7];
        #pragma unroll
        for (int e = 0; e < 7; ++e) {
            int m0 = 2*fr + 32*e;
            dvv[e] = (m0 < LL) ? *(const float2*)(dv + m0) : make_float2(0.f, 0.f);
        }
        auto dorow = [&](const float2 (&mk)[7], int l) {
            if (l < LL) {                       // uniform within 16-lane group
                float dl = dv[l];
                float sc[14]; float mx = -3e38f;
                #pragma unroll
                for (int e = 0; e < 7; ++e) {
                    int m0 = 2*fr + 32*e;
                    if (m0 < LL) {
                        unsigned w2 = *(const unsigned*)((const char*)Tb + ((size_t)l*232 + m0)*2);
                        float w0 = b2f((unsigned short)(w2 & 0xffffu));
                        float w1 = b2f((unsigned short)(w2 >> 16));
                        float s0 = -(fmaf(dl, dvv[e].x, -w0)*invden
                                     + ((m0 == l) ? dl : 0.f))*INV_SQRT_HEAD + mk[e].x;
                        float s1 = -(fmaf(dl, dvv[e].y, -w1)*invden
                                     + ((m0 + 1 == l) ? dl : 0.f))*INV_SQRT_HEAD + mk[e].y;
                        sc[2*e] = s0; sc[2*e + 1] = s1;
                        mx = fmaxf(mx, fmaxf(s0, s1));
                    } else { sc[2*e] = -3e38f; sc[2*e + 1] = -3e38f; }
                }
                mx = fmaxf(mx, __shfl_xor(mx, 1));
                mx = fmaxf(mx, __shfl_xor(mx, 2));
                mx = fmaxf(mx, __shfl_xor(mx, 4));
                mx = fmaxf(mx, __shfl_xor(mx, 8));
                float sum = 0.f;
                #pragma unroll
                for (int e = 0; e < 7; ++e) {
                    int m0 = 2*fr + 32*e;
                    if (m0 < LL) {
                        float e0 = __expf(sc[2*e] - mx);
                        float e1 = __expf(sc[2*e + 1] - mx);
                        sc[2*e] = e0; sc[2*e + 1] = e1;
                        sum += e0 + e1;
                    }
                }
                sum += __shfl_xor(sum, 1);
                sum += __shfl_xor(sum, 2);
                sum += __shfl_xor(sum, 4);
                sum += __shfl_xor(sum, 8);
                float isum = 1.0f / sum;
                #pragma unroll
                for (int e = 0; e < 7; ++e) {
                    int m0 = 2*fr + 32*e;
                    if (m0 < LL) {
                        unsigned pw = f2b2(sc[2*e]*isum, sc[2*e + 1]*isum);
                        *(unsigned*)((char*)Tb + ((size_t)l*232 + m0)*2) = pw;
                    }
                }
            }
        };
        dorow(mkr0, wv_*4 + g);                   // pass 0
        dorow(mkr1, 64 + wv_*4 + g);              // pass 1
        dorow(mkr2, 128 + wv_*4 + g);             // pass 2
        if (wv_ < 2) dorow(mkr3, 192 + wv_*4 + g);// pass 3 (rows 192-199)
        int sp = wv_;
        // x prefetch for LN (issued before the barrier; latency drained there)
        float xp[16];
        #pragma unroll
        for (int d2 = 0; d2 < 4; ++d2)
            #pragma unroll
            for (int reg = 0; reg < 4; ++reg) {
                int l = sp*16 + g*4 + reg;
                xp[d2*4 + reg] = (sp < 13 && l < LL)
                    ? x[((size_t)b*LL + l)*64 + d2*16 + fr] : 0.f;
            }
        __syncthreads();          // attn rows (written cross-wave) ready for PV
        if (sp < 13) {
            float bdv[4], gv[4], bev[4];
            #pragma unroll
            for (int d2 = 0; d2 < 4; ++d2) {
                bdv[d2] = bd[d2*16 + fr];
                gv[d2]  = gamma[d2*16 + fr];
                bev[d2] = beta[d2*16 + fr];
            }
            char* hb = smem + OFF_UB + wv_*1152;   // u16[16][36] per wave
            // PV: ctx(16x64) = attn(16x224) @ Vt^T
            f32x4 cacc[4];
            #pragma unroll
            for (int d2 = 0; d2 < 4; ++d2) { f32x4 z = {0.f,0.f,0.f,0.f}; cacc[d2] = z; }
            {
                const char* arow = (const char*)Tb + (size_t)(sp*16 + fr)*464;
                #pragma unroll
                for (int kt = 0; kt < 7; ++kt) {
                    short8v a = *(const short8v*)(arow + kt*64 + g*16);
                    #pragma unroll
                    for (int d2 = 0; d2 < 4; ++d2) {
                        short8v bb = *(const short8v*)((const char*)Vt + (d2*16 + fr)*464 + kt*64 + g*16);
                        cacc[d2] = __builtin_amdgcn_mfma_f32_16x16x32_bf16(a, bb, cacc[d2], 0, 0, 0);
                    }
                }
            }
            // out-proj via halfbuf: two K=32 halves
            f32x4 oacc[4];
            #pragma unroll
            for (int d2 = 0; d2 < 4; ++d2) { f32x4 z = {0.f,0.f,0.f,0.f}; oacc[d2] = z; }
            #pragma unroll
            for (int h = 0; h < 2; ++h) {
                #pragma unroll
                for (int d2 = 0; d2 < 2; ++d2)
                    #pragma unroll
                    for (int reg = 0; reg < 4; ++reg)
                        *(unsigned short*)(hb + ((g*4 + reg)*36 + d2*16 + fr)*2) = f2b(cacc[h*2 + d2][reg]);
                short8v a = *(const short8v*)(hb + fr*72 + g*16);
                #pragma unroll
                for (int d2 = 0; d2 < 4; ++d2) {
                    short8v bb = *(const short8v*)((const char*)Wdb + (d2*16 + fr)*144 + h*64 + g*16);
                    oacc[d2] = __builtin_amdgcn_mfma_f32_16x16x32_bf16(a, bb, oacc[d2], 0, 0, 0);
                }
            }
            // LN over 64 dims + residual + store
            #pragma unroll
            for (int reg = 0; reg < 4; ++reg) {
                int l = sp*16 + g*4 + reg;
                if (l < LL) {
                    float z0 = oacc[0][reg] + bdv[0] + xp[reg];
                    float z1 = oacc[1][reg] + bdv[1] + xp[4 + reg];
                    float z2 = oacc[2][reg] + bdv[2] + xp[8 + reg];
                    float z3 = oacc[3][reg] + bdv[3] + xp[12 + reg];
                    float s = z0 + z1 + z2 + z3;
                    s += __shfl_xor(s, 1); s += __shfl_xor(s, 2);
                    s += __shfl_xor(s, 4); s += __shfl_xor(s, 8);
                    float mu = s * (1.0f/64.0f);
                    float c0 = z0 - mu, c1 = z1 - mu, c2 = z2 - mu, c3 = z3 - mu;
                    float vs = c0*c0 + c1*c1 + c2*c2 + c3*c3;
                    vs += __shfl_xor(vs, 1); vs += __shfl_xor(vs, 2);
                    vs += __shfl_xor(vs, 4); vs += __shfl_xor(vs, 8);
                    float rstd = rsqrtf(vs * (1.0f/64.0f) + 1e-12f);
                    float* op = out + ((size_t)b*LL + l)*64 + fr;
                    op[0]  = fmaf(gv[0]*rstd, c0, bev[0]);
                    op[16] = fmaf(gv[1]*rstd, c1, bev[1]);
                    op[32] = fmaf(gv[2]*rstd, c2, bev[2]);
                    op[48] = fmaf(gv[3]*rstd, c3, bev[3]);
                }
            }
        }
    }
    #undef LK_TILE
}

// ---------------------------------------------------------------------------
extern "C" void kernel_launch(void* const* d_in, const int* in_sizes, int n_in,
                              void* d_out, int out_size, void* d_ws, size_t ws_size,
                              hipStream_t stream) {
    const float* x     = (const float*)d_in[0];
    const float* mask  = (const float*)d_in[1];
    const int*   ids   = (const int*)  d_in[2];
    const float* C     = (const float*)d_in[3];
    const float* Wq    = (const float*)d_in[4];
    const float* bq    = (const float*)d_in[5];
    const float* Wv    = (const float*)d_in[6];
    const float* bv    = (const float*)d_in[7];
    const float* Wd    = (const float*)d_in[8];
    const float* bd    = (const float*)d_in[9];
    const float* gamma = (const float*)d_in[10];
    const float* beta  = (const float*)d_in[11];
    float* out = (float*)d_out;

    unsigned short* Vb = (unsigned short*)d_ws;   // workspace (unused this round)

    mega_kernel<<<NB, 1024, LDS_TOTAL, stream>>>(x, mask, ids, C, Wq, bq, Wv, bv,
                                                 Wd, bd, gamma, beta, Vb, out);
}

// Round 14
// 60.758 us; speedup vs baseline: 1.0055x; 1.0055x over previous
//
#include <hip/hip_runtime.h>
#include <hip/hip_bf16.h>
#include <math.h>

// Problem constants
#define NB 256
#define LL 200
#define DD 64
#define ITEMS_N 10000
#define RANK 16
#define ALPHA 1.0001f
#define INV_ALPHA (1.0f/1.0001f)
#define INV_SQRT_HEAD 0.17677669529663687f  // 1/sqrt(32)

typedef __attribute__((ext_vector_type(8))) short short8v;
typedef __attribute__((ext_vector_type(4))) float f32x4;

static __device__ __forceinline__ unsigned short f2b(float f) {
    unsigned u = __float_as_uint(f);
    unsigned r = (u + 0x7fffu + ((u >> 16) & 1u)) >> 16;   // RNE
    return (unsigned short)r;
}
// HW packed convert: lo16 = bf16(a), hi16 = bf16(c); RNE — bit-identical to f2b
static __device__ __forceinline__ unsigned f2b2(float a, float c) {
    unsigned r;
    asm("v_cvt_pk_bf16_f32 %0, %1, %2" : "=v"(r) : "v"(a), "v"(c));
    return r;
}
static __device__ __forceinline__ float b2f(unsigned short h) {
    return __uint_as_float(((unsigned)h) << 16);
}

// LDS layout (bytes) for mega
#define OFF_A     0        // Abuf u16[208][72] : S2 (MFMA output), later Vt u16[64][232]
#define OFF_TB    29952    // Tb u16[208][232]
// scratch aliased in the head of Tb (Tb rows 0-29):
#define OFF_CL32  (OFF_TB + 0)       // f32[32][33] candidate Gram (4224 B), dead after 1bd
#define OFF_U32   (OFF_TB + 4224)    // f32[32][17] selection chol (2176 B), dead after 1bd
#define OFF_UTL   (OFF_TB + 6400)    // u16[16][232] U^T lo-part (7424 B, ends 13824),
                                     //   written 1bd, read ph.3 MFMA, dead at 4+5
// Lk tiles are written TRANSPOSED (Tb[col][row], Lk symmetric): liveness is on
// Cc: phases 1bd/3 take Cc>=2 (rows >=32), phase 4+5 takes Cc in {0,1}.
// COVERAGE: 1bd idx 0..95 (96) + ph3 idx 96..142 (47) = 143, plus 26 tiles
// Cc in {0,1} in ph.4+5 -> all 169 tile positions => Tb holds the FULL
// symmetric Lk (Tb[i][j] == Tb[j][i] bitwise, MFMA operand-swap invariant).
#define OFF_XB    (OFF_TB + 20000)   // u16[208][72] x bf16          (29952 B, ends 49952)
#define OFF_WQB   (OFF_TB + 49952)   // u16[64][72]  Wq bf16         ( 9216 B, ends 59168)
#define OFF_WVB   (OFF_TB + 59168)   // u16[64][72]  Wv bf16         ( 9216 B, ends 68384)
#define OFF_BQS   (OFF_TB + 68384)   // f32[64]
#define OFF_BVS   (OFF_TB + 68640)   // f32[64]  (scratch ends 68896 < 96512)
#define OFF_UL    126464   // Ul f32[200][16] -> later Wdb u16[64][72]
#define OFF_UB    139264   // Ub u16[208][16] (written 1bd); phase 10: per-wave halfbuf
                           //   u16[16][36] x 16 = 18,432 B (139264..157696 < dv at 160000)
#define OFF_PB    145920   // Pb u16[208][16] (written ph.7); before that hosts scratch:
#define OFF_MAUG  (OFF_PB + 0)       // f32[16][33] 2112 B (ph.3)
#define OFF_MINVT (OFF_PB + 2112)    // f32[16][20] Minv^T padded (1280 B, ph.3-5)
#define OFF_IDSL  (OFF_PB + 3392)    // int[200] (ph.0-1bd)
#define OFF_PIV   (OFF_PB + 4192)    // int[16]
#define OFF_INVSQ (OFF_PB + 4256)    // f32[16]
#define OFF_IDP   (OFF_PB + 4320)    // int[16] (ends 4384 < 6656)
#define OFF_ZB    152576   // Zb u16[16][232] (7424 B, ends 160000); 1bd->ph.3 hosts
                           //   U^T hi-part (alias); Z written 4+5. 232-stride (464 B
                           //   rows) makes fr-strided b128 reads 2-way bank-free.
#define OFF_UTH   OFF_ZB
#define OFF_DV    160000   // dv f32[208] (832 B)
#define OFF_RED   160832   // red f32[32]
#define OFF_SCAL  160960   // scal f32[4]
#define OFF_ZPAD  160976   // 64 B zeros
#define LDS_TOTAL 161040

// ---------------------------------------------------------------------------
// K_mega. R14 = R12 exact revert (best passing kernel, 60.99 us).
// R13's mask pass-2 hoist + explicit Z float4 reads were neutral-to-negative
// (prediction failed) and are removed. R9's s_setprio remains shelved (NaN).
// Final structure: 11 phases, 1 block/CU, 16 waves, LDS 161,040 B.
// ---------------------------------------------------------------------------
__global__ __launch_bounds__(1024) void mega_kernel(
        const float* __restrict__ x,    const float* __restrict__ mask,
        const int*   __restrict__ ids,  const float* __restrict__ C,
        const float* __restrict__ Wq,   const float* __restrict__ bq,
        const float* __restrict__ Wv,   const float* __restrict__ bv,
        const float* __restrict__ Wd,   const float* __restrict__ bd,
        const float* __restrict__ gamma,const float* __restrict__ beta,
        unsigned short* __restrict__ Vg, float* __restrict__ out) {
    extern __shared__ char smem[];
    unsigned short* Abuf = (unsigned short*)(smem + OFF_A);   // S2 then Vt
    unsigned short* Tb   = (unsigned short*)(smem + OFF_TB);
    float* Cl32  = (float*)(smem + OFF_CL32);
    float* U32l  = (float*)(smem + OFF_U32);
    unsigned short* xbu  = (unsigned short*)(smem + OFF_XB);
    unsigned short* Wqbu = (unsigned short*)(smem + OFF_WQB);
    unsigned short* Wvbu = (unsigned short*)(smem + OFF_WVB);
    float* bqs   = (float*)(smem + OFF_BQS);
    float* bvs   = (float*)(smem + OFF_BVS);
    float*          Ul   = (float*)(smem + OFF_UL);
    unsigned short* Wdb  = (unsigned short*)(smem + OFF_UL);  // alias (Ul dead)
    unsigned short* Ub   = (unsigned short*)(smem + OFF_UB);
    unsigned short* Pb   = (unsigned short*)(smem + OFF_PB);
    unsigned short* Zb   = (unsigned short*)(smem + OFF_ZB);
    float* dv   = (float*)(smem + OFF_DV);
    float* red  = (float*)(smem + OFF_RED);
    float* scal = (float*)(smem + OFF_SCAL);
    const short8v* zpad = (const short8v*)(smem + OFF_ZPAD);
    int*   idsl  = (int*)(smem + OFF_IDSL);
    int*   pivots= (int*)(smem + OFF_PIV);
    float* invsqv= (float*)(smem + OFF_INVSQ);
    int*   idpv  = (int*)(smem + OFF_IDP);
    float* Maug  = (float*)(smem + OFF_MAUG);
    float* MinvT = (float*)(smem + OFF_MINVT);

    int t = threadIdx.x;
    int b = blockIdx.x;
    int wv_ = t >> 6, lane = t & 63, fr = lane & 15, g = lane >> 4;

    // ---- -1) early Gram-gather issue (hides scattered-HBM latency under 0) ----
    int ga_ = t >> 5, gc_ = t & 31;
    float cgv;
    {
        int ia = ids[b*LL + ga_];
        int ic = ids[b*LL + gc_];
        cgv = C[(size_t)ia*ITEMS_N + ic];
    }

    // ---- 0) stage ids, x->bf16, Wq/Wv->bf16, biases; zero pads ----
    {
        float4 z4; z4.x = 0.f; z4.y = 0.f; z4.z = 0.f; z4.w = 0.f;
        // Tb rows 200-207 (3,712 B)
        float4* tz = (float4*)(smem + OFF_TB + 92800);
        for (int i = t; i < 232; i += 1024) tz[i] = z4;
        // Zb full region (also zero-pads U^T hi cols 200-231 for ph.3/7 MFMA)
        float4* zz = (float4*)Zb;
        for (int i = t; i < 464; i += 1024) zz[i] = z4;
        if (t < 4) ((float4*)(smem + OFF_ZPAD))[t] = z4;
        if (t < 64)  ((unsigned*)(smem + OFF_UB + 6400))[t] = 0;   // Ub rows 200-207
        // U^T-lo pad cols 200-223 (192 words; region untouched until 1bd writes)
        if (t < 192) {
            int s = t / 12, c2 = t - s*12;
            *(unsigned*)(smem + OFF_UTL + s*464 + 400 + c2*4) = 0;
        }
        // xb pad rows 200-207 (1,152 B)
        for (int i = t; i < 288; i += 1024) ((unsigned*)(smem + OFF_XB + 28800))[i] = 0;
        // x -> bf16 (float4-vectorized, packed cvt)
        const float4* x4p = (const float4*)(x + (size_t)b*12800);
        #pragma unroll
        for (int it2 = 0; it2 < 4; ++it2) {
            int i4 = t + it2*1024;
            if (i4 < 3200) {
                float4 v4 = x4p[i4];
                int r = i4 >> 4, k4 = (i4 & 15) << 2;
                *(uint2*)(xbu + r*72 + k4) =
                    make_uint2(f2b2(v4.x, v4.y), f2b2(v4.z, v4.w));
            }
        }
        // Wq/Wv -> bf16
        {
            float4 q4 = ((const float4*)Wq)[t];
            float4 w4 = ((const float4*)Wv)[t];
            int d2 = t >> 4, k4 = (t & 15) << 2;
            *(uint2*)(Wqbu + d2*72 + k4) = make_uint2(f2b2(q4.x, q4.y), f2b2(q4.z, q4.w));
            *(uint2*)(Wvbu + d2*72 + k4) = make_uint2(f2b2(w4.x, w4.y), f2b2(w4.z, w4.w));
        }
        if (t < 64) { bqs[t] = bq[t]; bvs[t] = bv[t]; }
        if (t < LL) idsl[t] = ids[b*LL + t];
        Cl32[ga_*33 + gc_] = cgv;     // gather landed during staging
    }
    __syncthreads();

    // ---- 0.5') wave 0: selection Cholesky (needs only Cl32 — ready now);
    //      waves 1-15: the 52 S2/V MFMA tiles; V held in packed regs. ----
    unsigned vpack[8];
    #pragma unroll
    for (int i = 0; i < 8; ++i) vpack[i] = 0;
    if (wv_ == 0) {
        int a = lane & 31;
        float diag = Cl32[a*33 + a] - 1.0f;
        float ur[16];
        int   mypiv = 0; float myinv = 0.f;
        bool  removed = false;
        #pragma unroll
        for (int s = 0; s < RANK; ++s) {
            float v = removed ? -3e38f : diag;
            int idx = a;
            #pragma unroll
            for (int off = 16; off > 0; off >>= 1) {
                float v2 = __shfl_xor(v, off);
                int   i2 = __shfl_xor(idx, off);
                if (v2 > v || (v2 == v && i2 < idx)) { v = v2; idx = i2; }
            }
            int p = idx; float dp = v;          // wave-uniform (p < 32)
            float iv = (dp < 1e-9f) ? 0.0f : (1.0f/sqrtf(dp));
            float c = Cl32[a*33 + p] - ((a == p) ? 1.0f : 0.0f);
            #pragma unroll
            for (int k = 0; k < s; ++k) {
                float upk = __shfl(ur[k], p);   // pivot row value U32[p][k]
                c -= ur[k] * upk;
            }
            float u = c * iv;
            ur[s] = u;
            diag -= u*u;
            if (a == p) removed = true;
            if (lane == s) { mypiv = p; myinv = iv; }
        }
        #pragma unroll
        for (int s = 0; s < RANK; ++s) U32l[a*17 + s] = ur[s];
        if (lane < 16) {
            pivots[lane] = mypiv;
            invsqv[lane] = myinv;
            idpv[lane]   = idsl[mypiv];
        }
    } else {
        #pragma unroll
        for (int it2 = 0; it2 < 4; ++it2) {
            int tile = (wv_ - 1) + 15*it2;
            if (tile < 52) {
                int R = tile >> 2, Dt = tile & 3;
                const char* ar = (const char*)smem + OFF_XB + (R*16 + fr)*144;
                const char* qr = (const char*)smem + OFF_WQB + (Dt*16 + fr)*144;
                const char* vr = (const char*)smem + OFF_WVB + (Dt*16 + fr)*144;
                short8v a0 = *(const short8v*)(ar + g*16);
                short8v a1 = *(const short8v*)(ar + 64 + g*16);
                f32x4 qa = {0.f,0.f,0.f,0.f};
                f32x4 va = {0.f,0.f,0.f,0.f};
                qa = __builtin_amdgcn_mfma_f32_16x16x32_bf16(a0, *(const short8v*)(qr + g*16), qa, 0,0,0);
                qa = __builtin_amdgcn_mfma_f32_16x16x32_bf16(a1, *(const short8v*)(qr + 64 + g*16), qa, 0,0,0);
                va = __builtin_amdgcn_mfma_f32_16x16x32_bf16(a0, *(const short8v*)(vr + g*16), va, 0,0,0);
                va = __builtin_amdgcn_mfma_f32_16x16x32_bf16(a1, *(const short8v*)(vr + 64 + g*16), va, 0,0,0);
                int col = Dt*16 + fr;
                float bqc = bqs[col], bvc = bvs[col];
                unsigned s01 = f2b2((qa[0]+bqc)*(qa[0]+bqc), (qa[1]+bqc)*(qa[1]+bqc));
                unsigned s23 = f2b2((qa[2]+bqc)*(qa[2]+bqc), (qa[3]+bqc)*(qa[3]+bqc));
                #pragma unroll
                for (int reg = 0; reg < 4; ++reg) {
                    int row = R*16 + g*4 + reg;
                    unsigned short sv = (unsigned short)
                        (((reg < 2 ? s01 : s23) >> ((reg & 1)*16)) & 0xffffu);
                    Abuf[row*72 + col] = (row < LL) ? sv : (unsigned short)0;
                }
                vpack[2*it2]     = f2b2(va[0] + bvc, va[1] + bvc);
                vpack[2*it2 + 1] = f2b2(va[2] + bvc, va[3] + bvc);
            }
        }
    }
    __syncthreads();

    // Lk tile macro: tile (R,Cc) written TRANSPOSED-PACKED to Tb[col][row0..3]
    #define LK_TILE(Ridx, Ccidx)                                               \
    {                                                                          \
        int R = (Ridx), Cc = (Ccidx);                                          \
        short8v a0 = *(const short8v*)((char*)Abuf + (R*16 + fr)*144 + g*16);  \
        short8v a1 = *(const short8v*)((char*)Abuf + (R*16 + fr)*144 + 64 + g*16); \
        short8v b0 = *(const short8v*)((char*)Abuf + (Cc*16 + fr)*144 + g*16); \
        short8v b1 = *(const short8v*)((char*)Abuf + (Cc*16 + fr)*144 + 64 + g*16); \
        f32x4 acc = {0.f, 0.f, 0.f, 0.f};                                      \
        acc = __builtin_amdgcn_mfma_f32_16x16x32_bf16(a0, b0, acc, 0, 0, 0);   \
        acc = __builtin_amdgcn_mfma_f32_16x16x32_bf16(a1, b1, acc, 0, 0, 0);   \
        int col = Cc*16 + fr, row0 = R*16 + g*4;                               \
        if (col < LL && row0 < LL) {                                           \
            *(uint2*)&Tb[col*232 + row0] =                                     \
                make_uint2(f2b2(acc[0], acc[1]), f2b2(acc[2], acc[3]));        \
        }                                                                      \
    }

    // ---- 1bd) waves 0-3: column-major pivot gather (C symmetric; 16 rows ->
    //      ~160 TLB pages) + U recursion, vectorized writes. Rows t<32 from
    //      Cl32. waves 4-15: 96 Lk tiles (idx 0..95, Cc>=2) under the gather. ----
    if (wv_ < 4) {
        if (t < LL) {
            float cg[16];
            if (t < 32) {
                #pragma unroll
                for (int s = 0; s < RANK; ++s) cg[s] = Cl32[t*33 + pivots[s]];
            } else {
                int myid = idsl[t];
                #pragma unroll
                for (int s = 0; s < RANK; ++s)
                    cg[s] = C[(size_t)idpv[s]*ITEMS_N + myid];
            }
            float ur[16];
            #pragma unroll
            for (int s = 0; s < RANK; ++s) {
                int p = pivots[s];
                float c = cg[s] - ((t == p) ? 1.0f : 0.0f);
                #pragma unroll
                for (int k = 0; k < s; ++k) c -= ur[k] * U32l[p*17 + k];
                ur[s] = c * invsqv[s];
            }
            unsigned short* Uth = (unsigned short*)(smem + OFF_UTH);
            unsigned short* Utl = (unsigned short*)(smem + OFF_UTL);
            // packed converts + vectorized Ul/Ub writes
            unsigned hp[8];
            #pragma unroll
            for (int s2 = 0; s2 < 8; ++s2) hp[s2] = f2b2(ur[2*s2], ur[2*s2 + 1]);
            float4* ul4 = (float4*)&Ul[t*RANK];
            ul4[0] = make_float4(ur[0],  ur[1],  ur[2],  ur[3]);
            ul4[1] = make_float4(ur[4],  ur[5],  ur[6],  ur[7]);
            ul4[2] = make_float4(ur[8],  ur[9],  ur[10], ur[11]);
            ul4[3] = make_float4(ur[12], ur[13], ur[14], ur[15]);
            uint4* ub4 = (uint4*)&Ub[t*RANK];
            ub4[0] = make_uint4(hp[0], hp[1], hp[2], hp[3]);
            ub4[1] = make_uint4(hp[4], hp[5], hp[6], hp[7]);
            #pragma unroll
            for (int s = 0; s < RANK; ++s) {
                unsigned short hv = (unsigned short)((hp[s >> 1] >> ((s & 1)*16)) & 0xffffu);
                Uth[s*232 + t] = hv;
                Utl[s*232 + t] = f2b(ur[s] - b2f(hv));
            }
        }
    } else {
        for (int idx = (wv_ - 4); idx < 96; idx += 12)
            LK_TILE(idx % 13, 2 + idx/13);
    }
    __syncthreads();

    // ---- 3) wave 0: M = alpha I + U^T U (split-bf16 MFMA) + 32-lane GJ
    //      (lanes 0-15 M rows, 16-31 inv rows; bit-identical arithmetic);
    //      waves 1-15: pad-zero rows 30-199 + 47 tiles (idx 96..142). ----
    if (wv_ == 0) {
        const char* uh  = smem + OFF_UTH;
        const char* ul2 = smem + OFF_UTL;
        f32x4 macc = {0.f,0.f,0.f,0.f};
        #pragma unroll
        for (int kb = 0; kb < 7; ++kb) {
            short8v h  = *(const short8v*)(uh  + fr*464 + kb*64 + g*16);
            short8v l2 = *(const short8v*)(ul2 + fr*464 + kb*64 + g*16);
            macc = __builtin_amdgcn_mfma_f32_16x16x32_bf16(h,  h,  macc, 0,0,0);
            macc = __builtin_amdgcn_mfma_f32_16x16x32_bf16(h,  l2, macc, 0,0,0);
            macc = __builtin_amdgcn_mfma_f32_16x16x32_bf16(l2, h,  macc, 0,0,0);
        }
        #pragma unroll
        for (int reg = 0; reg < 4; ++reg) {
            int r = g*4 + reg;
            Maug[r*33 + fr] = macc[reg] + ((r == fr) ? ALPHA : 0.f);
        }
        // 32-lane GJ: lanes 0-15 hold M rows, lanes 16-31 hold inverse rows
        float va[16];
        int rl = lane & 15;
        bool hi = (lane & 16) != 0;
        #pragma unroll
        for (int c = 0; c < 16; ++c)
            va[c] = hi ? ((rl == c) ? 1.0f : 0.0f) : Maug[rl*33 + c];
        #pragma unroll
        for (int s = 0; s < 16; ++s) {
            float pv = __shfl(va[s], s);          // M[s][s] (lane s, lo half)
            float f  = __shfl(va[s], rl);         // M[rl][s] (from lo lane rl)
            float pvinv = 1.0f / pv;
            int src = s + (hi ? 16 : 0);          // pivot row: M from s, inv from 16+s
            #pragma unroll
            for (int c = 0; c < 16; ++c) {
                float prow = __shfl(va[c], src) * pvinv;
                if (rl == s) va[c] = prow;
                else va[c] = fmaf(-f, prow, va[c]);
            }
        }
        if (hi && lane < 32) {
            // store TRANSPOSED, padded rows of 20 floats (16B-aligned)
            #pragma unroll
            for (int c = 0; c < 16; ++c) MinvT[c*20 + rl] = va[c];
        }
    } else {
        // Tb pad cols 200-231, rows 30-199 (above U^T-lo which ends 13824)
        for (int i = t - 64; i < 2720; i += 960) {
            int r = 30 + (i >> 4), c2 = i & 15;
            *(unsigned*)(smem + OFF_TB + r*464 + 400 + c2*4) = 0;
        }
        for (int idx = 96 + (wv_ - 1); idx < 143; idx += 15)
            LK_TILE(idx % 13, 2 + idx/13);
    }
    __syncthreads();

    // ---- 4+5) Wd reg-prefetch (T14; lands during Z/tiles, written ph.7) +
    //      Z = U*Minv -> Zb; 26 tiles Cc=0,1; pad rows 0-29. ----
    float4 wd4 = ((const float4*)Wd)[t];
    for (int idx = t; idx < LL*RANK; idx += 1024) {
        int i = idx >> 4, r = idx & 15;
        float acc = 0.f;
        #pragma unroll
        for (int k = 0; k < 16; ++k) acc = fmaf(Ul[i*RANK + k], MinvT[r*20 + k], acc);
        Zb[r*232 + i] = f2b(acc);
    }
    if (t < 480) {
        int r = t >> 4, c2 = t & 15;
        *(unsigned*)(smem + OFF_TB + r*464 + 400 + c2*4) = 0;
    }
    for (int u2 = wv_; u2 < 26; u2 += 16)
        LK_TILE(u2 % 13, u2 / 13);
    __syncthreads();            // MinvT read done; Tb holds full Lk + zero pads

    // ---- 7) mask pass-0 chunk prefetch (row wv_*4+g < 64; 14 regs) +
    //      Vt stage from held regs via packed b64 writes (S2 dead)
    //      + Wdb stage from wd4 (Ul dead; one uint2 store) + P = Lk@Z -> Pb ----
    float2 mkr0[7];
    {
        int l0 = wv_*4 + g;                       // pass-0 row, always < 64 < LL
        const float* mbase = mask + (size_t)b*40000;
        #pragma unroll
        for (int e = 0; e < 7; ++e) {
            int m0 = 2*fr + 32*e;
            mkr0[e] = (m0 < LL)
                ? *(const float2*)(mbase + (size_t)l0*200 + m0) : make_float2(0.f, 0.f);
        }
    }
    {
        unsigned short* Vt = Abuf;
        if (wv_ > 0) {
            #pragma unroll
            for (int it2 = 0; it2 < 4; ++it2) {
                int tile = (wv_ - 1) + 15*it2;
                if (tile < 52) {
                    int R = tile >> 2, Dt = tile & 3;
                    int row0 = R*16 + g*4;
                    if (row0 < LL) {   // uniform over the 4-row group (200 % 4 == 0)
                        *(uint2*)&Vt[(Dt*16 + fr)*232 + row0] =
                            make_uint2(vpack[2*it2], vpack[2*it2 + 1]);
                    }
                }
            }
        }
        for (int i = t; i < 2048; i += 1024) {
            int d = i >> 5, mc = i & 31;
            Vt[d*232 + 200 + mc] = 0;
        }
        {
            int d2 = t >> 4, k4 = (t & 15) << 2;
            *(uint2*)(Wdb + d2*72 + k4) =
                make_uint2(f2b2(wd4.x, wd4.y), f2b2(wd4.z, wd4.w));
        }
    }
    for (int strip = wv_; strip < 13; strip += 16) {
        f32x4 acc = {0.f, 0.f, 0.f, 0.f};
        const char* arow = (const char*)Tb + (size_t)(strip*16 + fr)*464;
        const char* brow = (const char*)Zb + (size_t)fr*464;
        #pragma unroll
        for (int kt = 0; kt < 7; ++kt) {
            short8v a  = *(const short8v*)(arow + kt*64 + g*16);
            short8v bb = *(const short8v*)(brow + kt*64 + g*16);
            acc = __builtin_amdgcn_mfma_f32_16x16x32_bf16(a, bb, acc, 0, 0, 0);
        }
        #pragma unroll
        for (int reg = 0; reg < 4; ++reg) {
            int prow = strip*16 + g*4 + reg;
            Pb[prow*16 + fr] = f2b(acc[reg]);
        }
    }
    __syncthreads();

    // ---- 8+9 fused, symmetric-Lk; mask pass-1 chunk prefetched here.
    //      lk read as ONE uint2 at the transposed position (Lk symmetric,
    //      bit-identical), replacing 4 scalar u16 reads. ----
    float2 mkr1[7];
    {
        int l1 = 64 + wv_*4 + g;                  // pass-1 row, 64..127 < LL
        const float* mbase = mask + (size_t)b*40000;
        #pragma unroll
        for (int e = 0; e < 7; ++e) {
            int m0 = 2*fr + 32*e;
            mkr1[e] = (m0 < LL)
                ? *(const float2*)(mbase + (size_t)l1*200 + m0) : make_float2(0.f, 0.f);
        }
    }
    {
        float ps = 0.f, psd = 0.f;
        for (int u = wv_; u < 91; u += 16) {
            int R, Cc;
            if (u < 13) { R = u; Cc = u; }
            else {
                int q = u - 13, rr = 0;
                while (q >= 12 - rr) { q -= 12 - rr; ++rr; }
                R = rr; Cc = rr + 1 + q;
            }
            const short8v* pPR = (g < 2) ? (const short8v*)((const char*)Pb + (R*16 + fr)*32 + g*16) : zpad;
            const short8v* pUC = (g < 2) ? (const short8v*)((const char*)Ub + (Cc*16 + fr)*32 + g*16) : zpad;
            const short8v* pUR = (g < 2) ? (const short8v*)((const char*)Ub + (R*16 + fr)*32 + g*16) : zpad;
            const short8v* pPC = (g < 2) ? (const short8v*)((const char*)Pb + (Cc*16 + fr)*32 + g*16) : zpad;
            f32x4 acc1 = {0.f,0.f,0.f,0.f};
            f32x4 acc2 = {0.f,0.f,0.f,0.f};
            acc1 = __builtin_amdgcn_mfma_f32_16x16x32_bf16(*pPR, *pUC, acc1, 0,0,0);  // (PU^T)[row][col]
            acc2 = __builtin_amdgcn_mfma_f32_16x16x32_bf16(*pUR, *pPC, acc2, 0,0,0);  // (PU^T)[col][row]
            int col = Cc*16 + fr, row0 = R*16 + g*4;
            // packed lk read from transposed (identical) position, own-tile addr
            uint2 lk2 = *(const uint2*)&Tb[col*232 + row0];
            if (u < 13) {
                #pragma unroll
                for (int reg = 0; reg < 4; ++reg) {
                    int row = row0 + reg;
                    float lk = b2f((unsigned short)
                        (((reg < 2 ? lk2.x : lk2.y) >> ((reg & 1)*16)) & 0xffffu));
                    float tvA = (lk - acc1[reg]) * INV_ALPHA;
                    float tvT = (lk - acc2[reg]) * INV_ALPHA;
                    if (row < LL && col < LL) {
                        float w = tvA * tvT;
                        Tb[row*232 + col] = f2b(w);
                        ps += w;
                        if (row == col) { dv[row] = tvA; psd += tvA; }
                    }
                }
            } else {
                // off-diagonal: rows = row0+reg <= 191 < LL always (R <= 11)
                float w[4];
                #pragma unroll
                for (int reg = 0; reg < 4; ++reg) {
                    float lk = b2f((unsigned short)
                        (((reg < 2 ? lk2.x : lk2.y) >> ((reg & 1)*16)) & 0xffffu));
                    float tvA = (lk - acc1[reg]) * INV_ALPHA;
                    float tvT = (lk - acc2[reg]) * INV_ALPHA;
                    w[reg] = tvA * tvT;
                }
                uint2 pk = make_uint2(f2b2(w[0], w[1]), f2b2(w[2], w[3]));
                if (col < LL) {
                    #pragma unroll
                    for (int reg = 0; reg < 4; ++reg) {
                        int row = row0 + reg;
                        Tb[row*232 + col] = (unsigned short)
                            (((reg < 2 ? pk.x : pk.y) >> ((reg & 1)*16)) & 0xffffu);
                        ps += 2.0f * w[reg];
                    }
                    *(uint2*)&Tb[col*232 + row0] = pk;   // W symmetric, packed b64
                }
            }
        }
        #pragma unroll
        for (int off = 32; off > 0; off >>= 1) {
            ps  += __shfl_xor(ps, off);
            psd += __shfl_xor(psd, off);
        }
        if (lane == 0) { red[wv_] = ps; red[16 + wv_] = psd; }
        __syncthreads();
        // parallel reduce: lanes 0-15 sum ps parts, 16-31 sum psd parts
        if (t < 32) {
            float v = red[t];
            v += __shfl_xor(v, 1);
            v += __shfl_xor(v, 2);
            v += __shfl_xor(v, 4);
            v += __shfl_xor(v, 8);
            float s1 = __shfl(v, 0);
            float s2 = __shfl(v, 16);
            if (t == 0) {
                float dn = fmaxf(0.5f*(s2*s2 - s1), 1e-9f);
                scal[0] = 1.0f / dn;
            }
        }
        __syncthreads();
    }

    // ---- 10) softmax: 4 passes over ALL 16 waves (row = p*64 + wv_*4 + g;
    //      passes 0-2 bound-free, pass 3 waves 0-1 only), then barrier,
    //      then PV -> proj -> LN on the 13 strip owners. ----
    {
        const unsigned short* Vt = Abuf;
        float invden = scal[0];
        // mask passes 2-3 (phase-local registers)
        float2 mkr2[7], mkr3[7];
        {
            const float* mbase = mask + (size_t)b*40000;
            int l2 = 128 + wv_*4 + g;             // 128..191 < LL
            int l3 = 192 + wv_*4 + g;             // valid only for wv_ < 2
            bool p3 = (wv_ < 2);
            #pragma unroll
            for (int e = 0; e < 7; ++e) {
                int m0 = 2*fr + 32*e;
                bool mm = (m0 < LL);
                mkr2[e] = mm         ? *(const float2*)(mbase + (size_t)l2*200 + m0) : make_float2(0.f, 0.f);
                mkr3[e] = (mm && p3) ? *(const float2*)(mbase + (size_t)l3*200 + m0) : make_float2(0.f, 0.f);
            }
        }
        // hoist dv pairs once (shared by all 4 passes)
        float2 dvv[7];
        #pragma unroll
        for (int e = 0; e < 7; ++e) {
            int m0 = 2*fr + 32*e;
            dvv[e] = (m0 < LL) ? *(const float2*)(dv + m0) : make_float2(0.f, 0.f);
        }
        auto dorow = [&](const float2 (&mk)[7], int l) {
            if (l < LL) {                       // uniform within 16-lane group
                float dl = dv[l];
                float sc[14]; float mx = -3e38f;
                #pragma unroll
                for (int e = 0; e < 7; ++e) {
                    int m0 = 2*fr + 32*e;
                    if (m0 < LL) {
                        unsigned w2 = *(const unsigned*)((const char*)Tb + ((size_t)l*232 + m0)*2);
                        float w0 = b2f((unsigned short)(w2 & 0xffffu));
                        float w1 = b2f((unsigned short)(w2 >> 16));
                        float s0 = -(fmaf(dl, dvv[e].x, -w0)*invden
                                     + ((m0 == l) ? dl : 0.f))*INV_SQRT_HEAD + mk[e].x;
                        float s1 = -(fmaf(dl, dvv[e].y, -w1)*invden
                                     + ((m0 + 1 == l) ? dl : 0.f))*INV_SQRT_HEAD + mk[e].y;
                        sc[2*e] = s0; sc[2*e + 1] = s1;
                        mx = fmaxf(mx, fmaxf(s0, s1));
                    } else { sc[2*e] = -3e38f; sc[2*e + 1] = -3e38f; }
                }
                mx = fmaxf(mx, __shfl_xor(mx, 1));
                mx = fmaxf(mx, __shfl_xor(mx, 2));
                mx = fmaxf(mx, __shfl_xor(mx, 4));
                mx = fmaxf(mx, __shfl_xor(mx, 8));
                float sum = 0.f;
                #pragma unroll
                for (int e = 0; e < 7; ++e) {
                    int m0 = 2*fr + 32*e;
                    if (m0 < LL) {
                        float e0 = __expf(sc[2*e] - mx);
                        float e1 = __expf(sc[2*e + 1] - mx);
                        sc[2*e] = e0; sc[2*e + 1] = e1;
                        sum += e0 + e1;
                    }
                }
                sum += __shfl_xor(sum, 1);
                sum += __shfl_xor(sum, 2);
                sum += __shfl_xor(sum, 4);
                sum += __shfl_xor(sum, 8);
                float isum = 1.0f / sum;
                #pragma unroll
                for (int e = 0; e < 7; ++e) {
                    int m0 = 2*fr + 32*e;
                    if (m0 < LL) {
                        unsigned pw = f2b2(sc[2*e]*isum, sc[2*e + 1]*isum);
                        *(unsigned*)((char*)Tb + ((size_t)l*232 + m0)*2) = pw;
                    }
                }
            }
        };
        dorow(mkr0, wv_*4 + g);                   // pass 0
        dorow(mkr1, 64 + wv_*4 + g);              // pass 1
        dorow(mkr2, 128 + wv_*4 + g);             // pass 2
        if (wv_ < 2) dorow(mkr3, 192 + wv_*4 + g);// pass 3 (rows 192-199)
        int sp = wv_;
        // x prefetch for LN (issued before the barrier; latency drained there)
        float xp[16];
        #pragma unroll
        for (int d2 = 0; d2 < 4; ++d2)
            #pragma unroll
            for (int reg = 0; reg < 4; ++reg) {
                int l = sp*16 + g*4 + reg;
                xp[d2*4 + reg] = (sp < 13 && l < LL)
                    ? x[((size_t)b*LL + l)*64 + d2*16 + fr] : 0.f;
            }
        __syncthreads();          // attn rows (written cross-wave) ready for PV
        if (sp < 13) {
            float bdv[4], gv[4], bev[4];
            #pragma unroll
            for (int d2 = 0; d2 < 4; ++d2) {
                bdv[d2] = bd[d2*16 + fr];
                gv[d2]  = gamma[d2*16 + fr];
                bev[d2] = beta[d2*16 + fr];
            }
            char* hb = smem + OFF_UB + wv_*1152;   // u16[16][36] per wave
            // PV: ctx(16x64) = attn(16x224) @ Vt^T
            f32x4 cacc[4];
            #pragma unroll
            for (int d2 = 0; d2 < 4; ++d2) { f32x4 z = {0.f,0.f,0.f,0.f}; cacc[d2] = z; }
            {
                const char* arow = (const char*)Tb + (size_t)(sp*16 + fr)*464;
                #pragma unroll
                for (int kt = 0; kt < 7; ++kt) {
                    short8v a = *(const short8v*)(arow + kt*64 + g*16);
                    #pragma unroll
                    for (int d2 = 0; d2 < 4; ++d2) {
                        short8v bb = *(const short8v*)((const char*)Vt + (d2*16 + fr)*464 + kt*64 + g*16);
                        cacc[d2] = __builtin_amdgcn_mfma_f32_16x16x32_bf16(a, bb, cacc[d2], 0, 0, 0);
                    }
                }
            }
            // out-proj via halfbuf: two K=32 halves
            f32x4 oacc[4];
            #pragma unroll
            for (int d2 = 0; d2 < 4; ++d2) { f32x4 z = {0.f,0.f,0.f,0.f}; oacc[d2] = z; }
            #pragma unroll
            for (int h = 0; h < 2; ++h) {
                #pragma unroll
                for (int d2 = 0; d2 < 2; ++d2)
                    #pragma unroll
                    for (int reg = 0; reg < 4; ++reg)
                        *(unsigned short*)(hb + ((g*4 + reg)*36 + d2*16 + fr)*2) = f2b(cacc[h*2 + d2][reg]);
                short8v a = *(const short8v*)(hb + fr*72 + g*16);
                #pragma unroll
                for (int d2 = 0; d2 < 4; ++d2) {
                    short8v bb = *(const short8v*)((const char*)Wdb + (d2*16 + fr)*144 + h*64 + g*16);
                    oacc[d2] = __builtin_amdgcn_mfma_f32_16x16x32_bf16(a, bb, oacc[d2], 0, 0, 0);
                }
            }
            // LN over 64 dims + residual + store
            #pragma unroll
            for (int reg = 0; reg < 4; ++reg) {
                int l = sp*16 + g*4 + reg;
                if (l < LL) {
                    float z0 = oacc[0][reg] + bdv[0] + xp[reg];
                    float z1 = oacc[1][reg] + bdv[1] + xp[4 + reg];
                    float z2 = oacc[2][reg] + bdv[2] + xp[8 + reg];
                    float z3 = oacc[3][reg] + bdv[3] + xp[12 + reg];
                    float s = z0 + z1 + z2 + z3;
                    s += __shfl_xor(s, 1); s += __shfl_xor(s, 2);
                    s += __shfl_xor(s, 4); s += __shfl_xor(s, 8);
                    float mu = s * (1.0f/64.0f);
                    float c0 = z0 - mu, c1 = z1 - mu, c2 = z2 - mu, c3 = z3 - mu;
                    float vs = c0*c0 + c1*c1 + c2*c2 + c3*c3;
                    vs += __shfl_xor(vs, 1); vs += __shfl_xor(vs, 2);
                    vs += __shfl_xor(vs, 4); vs += __shfl_xor(vs, 8);
                    float rstd = rsqrtf(vs * (1.0f/64.0f) + 1e-12f);
                    float* op = out + ((size_t)b*LL + l)*64 + fr;
                    op[0]  = fmaf(gv[0]*rstd, c0, bev[0]);
                    op[16] = fmaf(gv[1]*rstd, c1, bev[1]);
                    op[32] = fmaf(gv[2]*rstd, c2, bev[2]);
                    op[48] = fmaf(gv[3]*rstd, c3, bev[3]);
                }
            }
        }
    }
    #undef LK_TILE
}

// ---------------------------------------------------------------------------
extern "C" void kernel_launch(void* const* d_in, const int* in_sizes, int n_in,
                              void* d_out, int out_size, void* d_ws, size_t ws_size,
                              hipStream_t stream) {
    const float* x     = (const float*)d_in[0];
    const float* mask  = (const float*)d_in[1];
    const int*   ids   = (const int*)  d_in[2];
    const float* C     = (const float*)d_in[3];
    const float* Wq    = (const float*)d_in[4];
    const float* bq    = (const float*)d_in[5];
    const float* Wv    = (const float*)d_in[6];
    const float* bv    = (const float*)d_in[7];
    const float* Wd    = (const float*)d_in[8];
    const float* bd    = (const float*)d_in[9];
    const float* gamma = (const float*)d_in[10];
    const float* beta  = (const float*)d_in[11];
    float* out = (float*)d_out;

    unsigned short* Vb = (unsigned short*)d_ws;   // workspace (unused)

    mega_kernel<<<NB, 1024, LDS_TOTAL, stream>>>(x, mask, ids, C, Wq, bq, Wv, bv,
                                                 Wd, bd, gamma, beta, Vb, out);
}

// Round 15
// 60.619 us; speedup vs baseline: 1.0078x; 1.0023x over previous
//
#include <hip/hip_runtime.h>
#include <hip/hip_bf16.h>
#include <math.h>

// Problem constants
#define NB 256
#define LL 200
#define DD 64
#define ITEMS_N 10000
#define RANK 16
#define ALPHA 1.0001f
#define INV_ALPHA (1.0f/1.0001f)
#define INV_SQRT_HEAD 0.17677669529663687f  // 1/sqrt(32)

typedef __attribute__((ext_vector_type(8))) short short8v;
typedef __attribute__((ext_vector_type(4))) float f32x4;

static __device__ __forceinline__ unsigned short f2b(float f) {
    unsigned u = __float_as_uint(f);
    unsigned r = (u + 0x7fffu + ((u >> 16) & 1u)) >> 16;   // RNE
    return (unsigned short)r;
}
// HW packed convert: lo16 = bf16(a), hi16 = bf16(c); RNE — bit-identical to f2b
static __device__ __forceinline__ unsigned f2b2(float a, float c) {
    unsigned r;
    asm("v_cvt_pk_bf16_f32 %0, %1, %2" : "=v"(r) : "v"(a), "v"(c));
    return r;
}
static __device__ __forceinline__ float b2f(unsigned short h) {
    return __uint_as_float(((unsigned)h) << 16);
}

// LDS layout (bytes) for mega
#define OFF_A     0        // Abuf u16[208][72] : S2 (MFMA output), later Vt u16[64][232]
#define OFF_TB    29952    // Tb u16[208][232]
// scratch aliased in the head of Tb (Tb rows 0-29):
#define OFF_CL32  (OFF_TB + 0)       // f32[32][33] candidate Gram (4224 B), dead after 1bd
#define OFF_U32   (OFF_TB + 4224)    // f32[32][17] selection chol (2176 B), dead after 1bd
#define OFF_UTL   (OFF_TB + 6400)    // u16[16][232] U^T lo-part (7424 B, ends 13824),
                                     //   written 1bd, read ph.3 MFMA, dead at 4+5
// Lk tiles are written TRANSPOSED (Tb[col][row], Lk symmetric): liveness is on
// Cc: phases 1bd/3 take Cc>=2 (rows >=32), phase 4+5 takes Cc in {0,1}.
// COVERAGE: 1bd idx 0..95 (96) + ph3 idx 96..142 (47) = 143, plus 26 tiles
// Cc in {0,1} in ph.4+5 -> all 169 tile positions => Tb holds the FULL
// symmetric Lk (Tb[i][j] == Tb[j][i] bitwise, MFMA operand-swap invariant).
#define OFF_XB    (OFF_TB + 20000)   // u16[208][72] x bf16          (29952 B, ends 49952)
#define OFF_WQB   (OFF_TB + 49952)   // u16[64][72]  Wq bf16         ( 9216 B, ends 59168)
#define OFF_WVB   (OFF_TB + 59168)   // u16[64][72]  Wv bf16         ( 9216 B, ends 68384)
#define OFF_BQS   (OFF_TB + 68384)   // f32[64]
#define OFF_BVS   (OFF_TB + 68640)   // f32[64]  (scratch ends 68896 < 96512)
#define OFF_UL    126464   // Ul f32[200][16] -> later Wdb u16[64][72]
#define OFF_UB    139264   // Ub u16[208][16] (written 1bd); phase 10: per-wave halfbuf
                           //   u16[16][36] x 16 = 18,432 B (139264..157696 < dv at 160000)
#define OFF_PB    145920   // Pb u16[208][16] (written ph.7); before that hosts scratch:
#define OFF_MAUG  (OFF_PB + 0)       // f32[16][33] 2112 B (ph.3)
#define OFF_MINVT (OFF_PB + 2112)    // f32[16][20] Minv^T padded (1280 B, ph.3-5)
#define OFF_IDSL  (OFF_PB + 3392)    // int[200] (ph.0-1bd)
#define OFF_PIV   (OFF_PB + 4192)    // int[16]
#define OFF_INVSQ (OFF_PB + 4256)    // f32[16]
#define OFF_IDP   (OFF_PB + 4320)    // int[16] (ends 4384 < 6656)
#define OFF_ZB    152576   // Zb u16[16][232] (7424 B, ends 160000); 1bd->ph.3 hosts
                           //   U^T hi-part (alias); Z written 4+5. 232-stride (464 B
                           //   rows) makes fr-strided b128 reads 2-way bank-free.
#define OFF_UTH   OFF_ZB
#define OFF_DV    160000   // dv f32[208] (832 B)
#define OFF_RED   160832   // red f32[32]
#define OFF_SCAL  160960   // f32[4] (unused this round; kept for layout)
#define OFF_ZPAD  160976   // 64 B zeros
#define LDS_TOTAL 161040

// ---------------------------------------------------------------------------
// K_mega. R15 = R12/R14 +:
//  - scal-reduction barrier REMOVED: after the single barrier that publishes
//    red[32] + dv, EVERY wave redundantly shfl-tree-reduces red in-register
//    (lanes 0-31; same summation order -> bit-identical invden) and proceeds
//    straight into softmax. Deletes one full block barrier + scal round-trip.
// grid B, block 1024 (16 waves), dynamic LDS 161,040 B (1 block/CU).
// NOTE: s_setprio shelved (R9 NaN); mask pass-2 hoist shelved (R13 neutral).
// ---------------------------------------------------------------------------
__global__ __launch_bounds__(1024) void mega_kernel(
        const float* __restrict__ x,    const float* __restrict__ mask,
        const int*   __restrict__ ids,  const float* __restrict__ C,
        const float* __restrict__ Wq,   const float* __restrict__ bq,
        const float* __restrict__ Wv,   const float* __restrict__ bv,
        const float* __restrict__ Wd,   const float* __restrict__ bd,
        const float* __restrict__ gamma,const float* __restrict__ beta,
        unsigned short* __restrict__ Vg, float* __restrict__ out) {
    extern __shared__ char smem[];
    unsigned short* Abuf = (unsigned short*)(smem + OFF_A);   // S2 then Vt
    unsigned short* Tb   = (unsigned short*)(smem + OFF_TB);
    float* Cl32  = (float*)(smem + OFF_CL32);
    float* U32l  = (float*)(smem + OFF_U32);
    unsigned short* xbu  = (unsigned short*)(smem + OFF_XB);
    unsigned short* Wqbu = (unsigned short*)(smem + OFF_WQB);
    unsigned short* Wvbu = (unsigned short*)(smem + OFF_WVB);
    float* bqs   = (float*)(smem + OFF_BQS);
    float* bvs   = (float*)(smem + OFF_BVS);
    float*          Ul   = (float*)(smem + OFF_UL);
    unsigned short* Wdb  = (unsigned short*)(smem + OFF_UL);  // alias (Ul dead)
    unsigned short* Ub   = (unsigned short*)(smem + OFF_UB);
    unsigned short* Pb   = (unsigned short*)(smem + OFF_PB);
    unsigned short* Zb   = (unsigned short*)(smem + OFF_ZB);
    float* dv   = (float*)(smem + OFF_DV);
    float* red  = (float*)(smem + OFF_RED);
    const short8v* zpad = (const short8v*)(smem + OFF_ZPAD);
    int*   idsl  = (int*)(smem + OFF_IDSL);
    int*   pivots= (int*)(smem + OFF_PIV);
    float* invsqv= (float*)(smem + OFF_INVSQ);
    int*   idpv  = (int*)(smem + OFF_IDP);
    float* Maug  = (float*)(smem + OFF_MAUG);
    float* MinvT = (float*)(smem + OFF_MINVT);

    int t = threadIdx.x;
    int b = blockIdx.x;
    int wv_ = t >> 6, lane = t & 63, fr = lane & 15, g = lane >> 4;

    // ---- -1) early Gram-gather issue (hides scattered-HBM latency under 0) ----
    int ga_ = t >> 5, gc_ = t & 31;
    float cgv;
    {
        int ia = ids[b*LL + ga_];
        int ic = ids[b*LL + gc_];
        cgv = C[(size_t)ia*ITEMS_N + ic];
    }

    // ---- 0) stage ids, x->bf16, Wq/Wv->bf16, biases; zero pads ----
    {
        float4 z4; z4.x = 0.f; z4.y = 0.f; z4.z = 0.f; z4.w = 0.f;
        // Tb rows 200-207 (3,712 B)
        float4* tz = (float4*)(smem + OFF_TB + 92800);
        for (int i = t; i < 232; i += 1024) tz[i] = z4;
        // Zb full region (also zero-pads U^T hi cols 200-231 for ph.3/7 MFMA)
        float4* zz = (float4*)Zb;
        for (int i = t; i < 464; i += 1024) zz[i] = z4;
        if (t < 4) ((float4*)(smem + OFF_ZPAD))[t] = z4;
        if (t < 64)  ((unsigned*)(smem + OFF_UB + 6400))[t] = 0;   // Ub rows 200-207
        // U^T-lo pad cols 200-223 (192 words; region untouched until 1bd writes)
        if (t < 192) {
            int s = t / 12, c2 = t - s*12;
            *(unsigned*)(smem + OFF_UTL + s*464 + 400 + c2*4) = 0;
        }
        // xb pad rows 200-207 (1,152 B)
        for (int i = t; i < 288; i += 1024) ((unsigned*)(smem + OFF_XB + 28800))[i] = 0;
        // x -> bf16 (float4-vectorized, packed cvt)
        const float4* x4p = (const float4*)(x + (size_t)b*12800);
        #pragma unroll
        for (int it2 = 0; it2 < 4; ++it2) {
            int i4 = t + it2*1024;
            if (i4 < 3200) {
                float4 v4 = x4p[i4];
                int r = i4 >> 4, k4 = (i4 & 15) << 2;
                *(uint2*)(xbu + r*72 + k4) =
                    make_uint2(f2b2(v4.x, v4.y), f2b2(v4.z, v4.w));
            }
        }
        // Wq/Wv -> bf16
        {
            float4 q4 = ((const float4*)Wq)[t];
            float4 w4 = ((const float4*)Wv)[t];
            int d2 = t >> 4, k4 = (t & 15) << 2;
            *(uint2*)(Wqbu + d2*72 + k4) = make_uint2(f2b2(q4.x, q4.y), f2b2(q4.z, q4.w));
            *(uint2*)(Wvbu + d2*72 + k4) = make_uint2(f2b2(w4.x, w4.y), f2b2(w4.z, w4.w));
        }
        if (t < 64) { bqs[t] = bq[t]; bvs[t] = bv[t]; }
        if (t < LL) idsl[t] = ids[b*LL + t];
        Cl32[ga_*33 + gc_] = cgv;     // gather landed during staging
    }
    __syncthreads();

    // ---- 0.5') wave 0: selection Cholesky (needs only Cl32 — ready now);
    //      waves 1-15: the 52 S2/V MFMA tiles; V held in packed regs. ----
    unsigned vpack[8];
    #pragma unroll
    for (int i = 0; i < 8; ++i) vpack[i] = 0;
    if (wv_ == 0) {
        int a = lane & 31;
        float diag = Cl32[a*33 + a] - 1.0f;
        float ur[16];
        int   mypiv = 0; float myinv = 0.f;
        bool  removed = false;
        #pragma unroll
        for (int s = 0; s < RANK; ++s) {
            float v = removed ? -3e38f : diag;
            int idx = a;
            #pragma unroll
            for (int off = 16; off > 0; off >>= 1) {
                float v2 = __shfl_xor(v, off);
                int   i2 = __shfl_xor(idx, off);
                if (v2 > v || (v2 == v && i2 < idx)) { v = v2; idx = i2; }
            }
            int p = idx; float dp = v;          // wave-uniform (p < 32)
            float iv = (dp < 1e-9f) ? 0.0f : (1.0f/sqrtf(dp));
            float c = Cl32[a*33 + p] - ((a == p) ? 1.0f : 0.0f);
            #pragma unroll
            for (int k = 0; k < s; ++k) {
                float upk = __shfl(ur[k], p);   // pivot row value U32[p][k]
                c -= ur[k] * upk;
            }
            float u = c * iv;
            ur[s] = u;
            diag -= u*u;
            if (a == p) removed = true;
            if (lane == s) { mypiv = p; myinv = iv; }
        }
        #pragma unroll
        for (int s = 0; s < RANK; ++s) U32l[a*17 + s] = ur[s];
        if (lane < 16) {
            pivots[lane] = mypiv;
            invsqv[lane] = myinv;
            idpv[lane]   = idsl[mypiv];
        }
    } else {
        #pragma unroll
        for (int it2 = 0; it2 < 4; ++it2) {
            int tile = (wv_ - 1) + 15*it2;
            if (tile < 52) {
                int R = tile >> 2, Dt = tile & 3;
                const char* ar = (const char*)smem + OFF_XB + (R*16 + fr)*144;
                const char* qr = (const char*)smem + OFF_WQB + (Dt*16 + fr)*144;
                const char* vr = (const char*)smem + OFF_WVB + (Dt*16 + fr)*144;
                short8v a0 = *(const short8v*)(ar + g*16);
                short8v a1 = *(const short8v*)(ar + 64 + g*16);
                f32x4 qa = {0.f,0.f,0.f,0.f};
                f32x4 va = {0.f,0.f,0.f,0.f};
                qa = __builtin_amdgcn_mfma_f32_16x16x32_bf16(a0, *(const short8v*)(qr + g*16), qa, 0,0,0);
                qa = __builtin_amdgcn_mfma_f32_16x16x32_bf16(a1, *(const short8v*)(qr + 64 + g*16), qa, 0,0,0);
                va = __builtin_amdgcn_mfma_f32_16x16x32_bf16(a0, *(const short8v*)(vr + g*16), va, 0,0,0);
                va = __builtin_amdgcn_mfma_f32_16x16x32_bf16(a1, *(const short8v*)(vr + 64 + g*16), va, 0,0,0);
                int col = Dt*16 + fr;
                float bqc = bqs[col], bvc = bvs[col];
                unsigned s01 = f2b2((qa[0]+bqc)*(qa[0]+bqc), (qa[1]+bqc)*(qa[1]+bqc));
                unsigned s23 = f2b2((qa[2]+bqc)*(qa[2]+bqc), (qa[3]+bqc)*(qa[3]+bqc));
                #pragma unroll
                for (int reg = 0; reg < 4; ++reg) {
                    int row = R*16 + g*4 + reg;
                    unsigned short sv = (unsigned short)
                        (((reg < 2 ? s01 : s23) >> ((reg & 1)*16)) & 0xffffu);
                    Abuf[row*72 + col] = (row < LL) ? sv : (unsigned short)0;
                }
                vpack[2*it2]     = f2b2(va[0] + bvc, va[1] + bvc);
                vpack[2*it2 + 1] = f2b2(va[2] + bvc, va[3] + bvc);
            }
        }
    }
    __syncthreads();

    // Lk tile macro: tile (R,Cc) written TRANSPOSED-PACKED to Tb[col][row0..3]
    #define LK_TILE(Ridx, Ccidx)                                               \
    {                                                                          \
        int R = (Ridx), Cc = (Ccidx);                                          \
        short8v a0 = *(const short8v*)((char*)Abuf + (R*16 + fr)*144 + g*16);  \
        short8v a1 = *(const short8v*)((char*)Abuf + (R*16 + fr)*144 + 64 + g*16); \
        short8v b0 = *(const short8v*)((char*)Abuf + (Cc*16 + fr)*144 + g*16); \
        short8v b1 = *(const short8v*)((char*)Abuf + (Cc*16 + fr)*144 + 64 + g*16); \
        f32x4 acc = {0.f, 0.f, 0.f, 0.f};                                      \
        acc = __builtin_amdgcn_mfma_f32_16x16x32_bf16(a0, b0, acc, 0, 0, 0);   \
        acc = __builtin_amdgcn_mfma_f32_16x16x32_bf16(a1, b1, acc, 0, 0, 0);   \
        int col = Cc*16 + fr, row0 = R*16 + g*4;                               \
        if (col < LL && row0 < LL) {                                           \
            *(uint2*)&Tb[col*232 + row0] =                                     \
                make_uint2(f2b2(acc[0], acc[1]), f2b2(acc[2], acc[3]));        \
        }                                                                      \
    }

    // ---- 1bd) waves 0-3: column-major pivot gather (C symmetric; 16 rows ->
    //      ~160 TLB pages) + U recursion, vectorized writes. Rows t<32 from
    //      Cl32. waves 4-15: 96 Lk tiles (idx 0..95, Cc>=2) under the gather. ----
    if (wv_ < 4) {
        if (t < LL) {
            float cg[16];
            if (t < 32) {
                #pragma unroll
                for (int s = 0; s < RANK; ++s) cg[s] = Cl32[t*33 + pivots[s]];
            } else {
                int myid = idsl[t];
                #pragma unroll
                for (int s = 0; s < RANK; ++s)
                    cg[s] = C[(size_t)idpv[s]*ITEMS_N + myid];
            }
            float ur[16];
            #pragma unroll
            for (int s = 0; s < RANK; ++s) {
                int p = pivots[s];
                float c = cg[s] - ((t == p) ? 1.0f : 0.0f);
                #pragma unroll
                for (int k = 0; k < s; ++k) c -= ur[k] * U32l[p*17 + k];
                ur[s] = c * invsqv[s];
            }
            unsigned short* Uth = (unsigned short*)(smem + OFF_UTH);
            unsigned short* Utl = (unsigned short*)(smem + OFF_UTL);
            // packed converts + vectorized Ul/Ub writes
            unsigned hp[8];
            #pragma unroll
            for (int s2 = 0; s2 < 8; ++s2) hp[s2] = f2b2(ur[2*s2], ur[2*s2 + 1]);
            float4* ul4 = (float4*)&Ul[t*RANK];
            ul4[0] = make_float4(ur[0],  ur[1],  ur[2],  ur[3]);
            ul4[1] = make_float4(ur[4],  ur[5],  ur[6],  ur[7]);
            ul4[2] = make_float4(ur[8],  ur[9],  ur[10], ur[11]);
            ul4[3] = make_float4(ur[12], ur[13], ur[14], ur[15]);
            uint4* ub4 = (uint4*)&Ub[t*RANK];
            ub4[0] = make_uint4(hp[0], hp[1], hp[2], hp[3]);
            ub4[1] = make_uint4(hp[4], hp[5], hp[6], hp[7]);
            #pragma unroll
            for (int s = 0; s < RANK; ++s) {
                unsigned short hv = (unsigned short)((hp[s >> 1] >> ((s & 1)*16)) & 0xffffu);
                Uth[s*232 + t] = hv;
                Utl[s*232 + t] = f2b(ur[s] - b2f(hv));
            }
        }
    } else {
        for (int idx = (wv_ - 4); idx < 96; idx += 12)
            LK_TILE(idx % 13, 2 + idx/13);
    }
    __syncthreads();

    // ---- 3) wave 0: M = alpha I + U^T U (split-bf16 MFMA) + 32-lane GJ
    //      (lanes 0-15 M rows, 16-31 inv rows; bit-identical arithmetic);
    //      waves 1-15: pad-zero rows 30-199 + 47 tiles (idx 96..142). ----
    if (wv_ == 0) {
        const char* uh  = smem + OFF_UTH;
        const char* ul2 = smem + OFF_UTL;
        f32x4 macc = {0.f,0.f,0.f,0.f};
        #pragma unroll
        for (int kb = 0; kb < 7; ++kb) {
            short8v h  = *(const short8v*)(uh  + fr*464 + kb*64 + g*16);
            short8v l2 = *(const short8v*)(ul2 + fr*464 + kb*64 + g*16);
            macc = __builtin_amdgcn_mfma_f32_16x16x32_bf16(h,  h,  macc, 0,0,0);
            macc = __builtin_amdgcn_mfma_f32_16x16x32_bf16(h,  l2, macc, 0,0,0);
            macc = __builtin_amdgcn_mfma_f32_16x16x32_bf16(l2, h,  macc, 0,0,0);
        }
        #pragma unroll
        for (int reg = 0; reg < 4; ++reg) {
            int r = g*4 + reg;
            Maug[r*33 + fr] = macc[reg] + ((r == fr) ? ALPHA : 0.f);
        }
        // 32-lane GJ: lanes 0-15 hold M rows, lanes 16-31 hold inverse rows
        float va[16];
        int rl = lane & 15;
        bool hi = (lane & 16) != 0;
        #pragma unroll
        for (int c = 0; c < 16; ++c)
            va[c] = hi ? ((rl == c) ? 1.0f : 0.0f) : Maug[rl*33 + c];
        #pragma unroll
        for (int s = 0; s < 16; ++s) {
            float pv = __shfl(va[s], s);          // M[s][s] (lane s, lo half)
            float f  = __shfl(va[s], rl);         // M[rl][s] (from lo lane rl)
            float pvinv = 1.0f / pv;
            int src = s + (hi ? 16 : 0);          // pivot row: M from s, inv from 16+s
            #pragma unroll
            for (int c = 0; c < 16; ++c) {
                float prow = __shfl(va[c], src) * pvinv;
                if (rl == s) va[c] = prow;
                else va[c] = fmaf(-f, prow, va[c]);
            }
        }
        if (hi && lane < 32) {
            // store TRANSPOSED, padded rows of 20 floats (16B-aligned)
            #pragma unroll
            for (int c = 0; c < 16; ++c) MinvT[c*20 + rl] = va[c];
        }
    } else {
        // Tb pad cols 200-231, rows 30-199 (above U^T-lo which ends 13824)
        for (int i = t - 64; i < 2720; i += 960) {
            int r = 30 + (i >> 4), c2 = i & 15;
            *(unsigned*)(smem + OFF_TB + r*464 + 400 + c2*4) = 0;
        }
        for (int idx = 96 + (wv_ - 1); idx < 143; idx += 15)
            LK_TILE(idx % 13, 2 + idx/13);
    }
    __syncthreads();

    // ---- 4+5) Wd reg-prefetch (T14; lands during Z/tiles, written ph.7) +
    //      Z = U*Minv -> Zb; 26 tiles Cc=0,1; pad rows 0-29. ----
    float4 wd4 = ((const float4*)Wd)[t];
    for (int idx = t; idx < LL*RANK; idx += 1024) {
        int i = idx >> 4, r = idx & 15;
        float acc = 0.f;
        #pragma unroll
        for (int k = 0; k < 16; ++k) acc = fmaf(Ul[i*RANK + k], MinvT[r*20 + k], acc);
        Zb[r*232 + i] = f2b(acc);
    }
    if (t < 480) {
        int r = t >> 4, c2 = t & 15;
        *(unsigned*)(smem + OFF_TB + r*464 + 400 + c2*4) = 0;
    }
    for (int u2 = wv_; u2 < 26; u2 += 16)
        LK_TILE(u2 % 13, u2 / 13);
    __syncthreads();            // MinvT read done; Tb holds full Lk + zero pads

    // ---- 7) mask pass-0 chunk prefetch (row wv_*4+g < 64; 14 regs) +
    //      Vt stage from held regs via packed b64 writes (S2 dead)
    //      + Wdb stage from wd4 (Ul dead; one uint2 store) + P = Lk@Z -> Pb ----
    float2 mkr0[7];
    {
        int l0 = wv_*4 + g;                       // pass-0 row, always < 64 < LL
        const float* mbase = mask + (size_t)b*40000;
        #pragma unroll
        for (int e = 0; e < 7; ++e) {
            int m0 = 2*fr + 32*e;
            mkr0[e] = (m0 < LL)
                ? *(const float2*)(mbase + (size_t)l0*200 + m0) : make_float2(0.f, 0.f);
        }
    }
    {
        unsigned short* Vt = Abuf;
        if (wv_ > 0) {
            #pragma unroll
            for (int it2 = 0; it2 < 4; ++it2) {
                int tile = (wv_ - 1) + 15*it2;
                if (tile < 52) {
                    int R = tile >> 2, Dt = tile & 3;
                    int row0 = R*16 + g*4;
                    if (row0 < LL) {   // uniform over the 4-row group (200 % 4 == 0)
                        *(uint2*)&Vt[(Dt*16 + fr)*232 + row0] =
                            make_uint2(vpack[2*it2], vpack[2*it2 + 1]);
                    }
                }
            }
        }
        for (int i = t; i < 2048; i += 1024) {
            int d = i >> 5, mc = i & 31;
            Vt[d*232 + 200 + mc] = 0;
        }
        {
            int d2 = t >> 4, k4 = (t & 15) << 2;
            *(uint2*)(Wdb + d2*72 + k4) =
                make_uint2(f2b2(wd4.x, wd4.y), f2b2(wd4.z, wd4.w));
        }
    }
    for (int strip = wv_; strip < 13; strip += 16) {
        f32x4 acc = {0.f, 0.f, 0.f, 0.f};
        const char* arow = (const char*)Tb + (size_t)(strip*16 + fr)*464;
        const char* brow = (const char*)Zb + (size_t)fr*464;
        #pragma unroll
        for (int kt = 0; kt < 7; ++kt) {
            short8v a  = *(const short8v*)(arow + kt*64 + g*16);
            short8v bb = *(const short8v*)(brow + kt*64 + g*16);
            acc = __builtin_amdgcn_mfma_f32_16x16x32_bf16(a, bb, acc, 0, 0, 0);
        }
        #pragma unroll
        for (int reg = 0; reg < 4; ++reg) {
            int prow = strip*16 + g*4 + reg;
            Pb[prow*16 + fr] = f2b(acc[reg]);
        }
    }
    __syncthreads();

    // ---- 8+9 fused, symmetric-Lk; mask pass-1 chunk prefetched here.
    //      lk read as ONE uint2 at the transposed position (Lk symmetric). ----
    float2 mkr1[7];
    {
        int l1 = 64 + wv_*4 + g;                  // pass-1 row, 64..127 < LL
        const float* mbase = mask + (size_t)b*40000;
        #pragma unroll
        for (int e = 0; e < 7; ++e) {
            int m0 = 2*fr + 32*e;
            mkr1[e] = (m0 < LL)
                ? *(const float2*)(mbase + (size_t)l1*200 + m0) : make_float2(0.f, 0.f);
        }
    }
    float invden;                                 // computed per-wave below
    {
        float ps = 0.f, psd = 0.f;
        for (int u = wv_; u < 91; u += 16) {
            int R, Cc;
            if (u < 13) { R = u; Cc = u; }
            else {
                int q = u - 13, rr = 0;
                while (q >= 12 - rr) { q -= 12 - rr; ++rr; }
                R = rr; Cc = rr + 1 + q;
            }
            const short8v* pPR = (g < 2) ? (const short8v*)((const char*)Pb + (R*16 + fr)*32 + g*16) : zpad;
            const short8v* pUC = (g < 2) ? (const short8v*)((const char*)Ub + (Cc*16 + fr)*32 + g*16) : zpad;
            const short8v* pUR = (g < 2) ? (const short8v*)((const char*)Ub + (R*16 + fr)*32 + g*16) : zpad;
            const short8v* pPC = (g < 2) ? (const short8v*)((const char*)Pb + (Cc*16 + fr)*32 + g*16) : zpad;
            f32x4 acc1 = {0.f,0.f,0.f,0.f};
            f32x4 acc2 = {0.f,0.f,0.f,0.f};
            acc1 = __builtin_amdgcn_mfma_f32_16x16x32_bf16(*pPR, *pUC, acc1, 0,0,0);  // (PU^T)[row][col]
            acc2 = __builtin_amdgcn_mfma_f32_16x16x32_bf16(*pUR, *pPC, acc2, 0,0,0);  // (PU^T)[col][row]
            int col = Cc*16 + fr, row0 = R*16 + g*4;
            // packed lk read from transposed (identical) position, own-tile addr
            uint2 lk2 = *(const uint2*)&Tb[col*232 + row0];
            if (u < 13) {
                #pragma unroll
                for (int reg = 0; reg < 4; ++reg) {
                    int row = row0 + reg;
                    float lk = b2f((unsigned short)
                        (((reg < 2 ? lk2.x : lk2.y) >> ((reg & 1)*16)) & 0xffffu));
                    float tvA = (lk - acc1[reg]) * INV_ALPHA;
                    float tvT = (lk - acc2[reg]) * INV_ALPHA;
                    if (row < LL && col < LL) {
                        float w = tvA * tvT;
                        Tb[row*232 + col] = f2b(w);
                        ps += w;
                        if (row == col) { dv[row] = tvA; psd += tvA; }
                    }
                }
            } else {
                // off-diagonal: rows = row0+reg <= 191 < LL always (R <= 11)
                float w[4];
                #pragma unroll
                for (int reg = 0; reg < 4; ++reg) {
                    float lk = b2f((unsigned short)
                        (((reg < 2 ? lk2.x : lk2.y) >> ((reg & 1)*16)) & 0xffffu));
                    float tvA = (lk - acc1[reg]) * INV_ALPHA;
                    float tvT = (lk - acc2[reg]) * INV_ALPHA;
                    w[reg] = tvA * tvT;
                }
                uint2 pk = make_uint2(f2b2(w[0], w[1]), f2b2(w[2], w[3]));
                if (col < LL) {
                    #pragma unroll
                    for (int reg = 0; reg < 4; ++reg) {
                        int row = row0 + reg;
                        Tb[row*232 + col] = (unsigned short)
                            (((reg < 2 ? pk.x : pk.y) >> ((reg & 1)*16)) & 0xffffu);
                        ps += 2.0f * w[reg];
                    }
                    *(uint2*)&Tb[col*232 + row0] = pk;   // W symmetric, packed b64
                }
            }
        }
        #pragma unroll
        for (int off = 32; off > 0; off >>= 1) {
            ps  += __shfl_xor(ps, off);
            psd += __shfl_xor(psd, off);
        }
        if (lane == 0) { red[wv_] = ps; red[16 + wv_] = psd; }
        __syncthreads();          // publishes red[32] + dv + W (single barrier)
        // EVERY wave redundantly reduces red (same tree order -> bit-identical):
        {
            float v = (lane < 32) ? red[lane] : 0.f;
            v += __shfl_xor(v, 1);
            v += __shfl_xor(v, 2);
            v += __shfl_xor(v, 4);
            v += __shfl_xor(v, 8);
            float s1 = __shfl(v, 0);
            float s2 = __shfl(v, 16);
            float dn = fmaxf(0.5f*(s2*s2 - s1), 1e-9f);
            invden = 1.0f / dn;
        }
    }

    // ---- 10) softmax: 4 passes over ALL 16 waves (row = p*64 + wv_*4 + g;
    //      passes 0-2 bound-free, pass 3 waves 0-1 only), then barrier,
    //      then PV -> proj -> LN on the 13 strip owners. ----
    {
        const unsigned short* Vt = Abuf;
        // mask passes 2-3 (phase-local registers)
        float2 mkr2[7], mkr3[7];
        {
            const float* mbase = mask + (size_t)b*40000;
            int l2 = 128 + wv_*4 + g;             // 128..191 < LL
            int l3 = 192 + wv_*4 + g;             // valid only for wv_ < 2
            bool p3 = (wv_ < 2);
            #pragma unroll
            for (int e = 0; e < 7; ++e) {
                int m0 = 2*fr + 32*e;
                bool mm = (m0 < LL);
                mkr2[e] = mm         ? *(const float2*)(mbase + (size_t)l2*200 + m0) : make_float2(0.f, 0.f);
                mkr3[e] = (mm && p3) ? *(const float2*)(mbase + (size_t)l3*200 + m0) : make_float2(0.f, 0.f);
            }
        }
        // hoist dv pairs once (shared by all 4 passes)
        float2 dvv[7];
        #pragma unroll
        for (int e = 0; e < 7; ++e) {
            int m0 = 2*fr + 32*e;
            dvv[e] = (m0 < LL) ? *(const float2*)(dv + m0) : make_float2(0.f, 0.f);
        }
        auto dorow = [&](const float2 (&mk)[7], int l) {
            if (l < LL) {                       // uniform within 16-lane group
                float dl = dv[l];
                float sc[14]; float mx = -3e38f;
                #pragma unroll
                for (int e = 0; e < 7; ++e) {
                    int m0 = 2*fr + 32*e;
                    if (m0 < LL) {
                        unsigned w2 = *(const unsigned*)((const char*)Tb + ((size_t)l*232 + m0)*2);
                        float w0 = b2f((unsigned short)(w2 & 0xffffu));
                        float w1 = b2f((unsigned short)(w2 >> 16));
                        float s0 = -(fmaf(dl, dvv[e].x, -w0)*invden
                                     + ((m0 == l) ? dl : 0.f))*INV_SQRT_HEAD + mk[e].x;
                        float s1 = -(fmaf(dl, dvv[e].y, -w1)*invden
                                     + ((m0 + 1 == l) ? dl : 0.f))*INV_SQRT_HEAD + mk[e].y;
                        sc[2*e] = s0; sc[2*e + 1] = s1;
                        mx = fmaxf(mx, fmaxf(s0, s1));
                    } else { sc[2*e] = -3e38f; sc[2*e + 1] = -3e38f; }
                }
                mx = fmaxf(mx, __shfl_xor(mx, 1));
                mx = fmaxf(mx, __shfl_xor(mx, 2));
                mx = fmaxf(mx, __shfl_xor(mx, 4));
                mx = fmaxf(mx, __shfl_xor(mx, 8));
                float sum = 0.f;
                #pragma unroll
                for (int e = 0; e < 7; ++e) {
                    int m0 = 2*fr + 32*e;
                    if (m0 < LL) {
                        float e0 = __expf(sc[2*e] - mx);
                        float e1 = __expf(sc[2*e + 1] - mx);
                        sc[2*e] = e0; sc[2*e + 1] = e1;
                        sum += e0 + e1;
                    }
                }
                sum += __shfl_xor(sum, 1);
                sum += __shfl_xor(sum, 2);
                sum += __shfl_xor(sum, 4);
                sum += __shfl_xor(sum, 8);
                float isum = 1.0f / sum;
                #pragma unroll
                for (int e = 0; e < 7; ++e) {
                    int m0 = 2*fr + 32*e;
                    if (m0 < LL) {
                        unsigned pw = f2b2(sc[2*e]*isum, sc[2*e + 1]*isum);
                        *(unsigned*)((char*)Tb + ((size_t)l*232 + m0)*2) = pw;
                    }
                }
            }
        };
        dorow(mkr0, wv_*4 + g);                   // pass 0
        dorow(mkr1, 64 + wv_*4 + g);              // pass 1
        dorow(mkr2, 128 + wv_*4 + g);             // pass 2
        if (wv_ < 2) dorow(mkr3, 192 + wv_*4 + g);// pass 3 (rows 192-199)
        int sp = wv_;
        // x prefetch for LN (issued before the barrier; latency drained there)
        float xp[16];
        #pragma unroll
        for (int d2 = 0; d2 < 4; ++d2)
            #pragma unroll
            for (int reg = 0; reg < 4; ++reg) {
                int l = sp*16 + g*4 + reg;
                xp[d2*4 + reg] = (sp < 13 && l < LL)
                    ? x[((size_t)b*LL + l)*64 + d2*16 + fr] : 0.f;
            }
        __syncthreads();          // attn rows (written cross-wave) ready for PV
        if (sp < 13) {
            float bdv[4], gv[4], bev[4];
            #pragma unroll
            for (int d2 = 0; d2 < 4; ++d2) {
                bdv[d2] = bd[d2*16 + fr];
                gv[d2]  = gamma[d2*16 + fr];
                bev[d2] = beta[d2*16 + fr];
            }
            char* hb = smem + OFF_UB + wv_*1152;   // u16[16][36] per wave
            // PV: ctx(16x64) = attn(16x224) @ Vt^T
            f32x4 cacc[4];
            #pragma unroll
            for (int d2 = 0; d2 < 4; ++d2) { f32x4 z = {0.f,0.f,0.f,0.f}; cacc[d2] = z; }
            {
                const char* arow = (const char*)Tb + (size_t)(sp*16 + fr)*464;
                #pragma unroll
                for (int kt = 0; kt < 7; ++kt) {
                    short8v a = *(const short8v*)(arow + kt*64 + g*16);
                    #pragma unroll
                    for (int d2 = 0; d2 < 4; ++d2) {
                        short8v bb = *(const short8v*)((const char*)Vt + (d2*16 + fr)*464 + kt*64 + g*16);
                        cacc[d2] = __builtin_amdgcn_mfma_f32_16x16x32_bf16(a, bb, cacc[d2], 0, 0, 0);
                    }
                }
            }
            // out-proj via halfbuf: two K=32 halves
            f32x4 oacc[4];
            #pragma unroll
            for (int d2 = 0; d2 < 4; ++d2) { f32x4 z = {0.f,0.f,0.f,0.f}; oacc[d2] = z; }
            #pragma unroll
            for (int h = 0; h < 2; ++h) {
                #pragma unroll
                for (int d2 = 0; d2 < 2; ++d2)
                    #pragma unroll
                    for (int reg = 0; reg < 4; ++reg)
                        *(unsigned short*)(hb + ((g*4 + reg)*36 + d2*16 + fr)*2) = f2b(cacc[h*2 + d2][reg]);
                short8v a = *(const short8v*)(hb + fr*72 + g*16);
                #pragma unroll
                for (int d2 = 0; d2 < 4; ++d2) {
                    short8v bb = *(const short8v*)((const char*)Wdb + (d2*16 + fr)*144 + h*64 + g*16);
                    oacc[d2] = __builtin_amdgcn_mfma_f32_16x16x32_bf16(a, bb, oacc[d2], 0, 0, 0);
                }
            }
            // LN over 64 dims + residual + store
            #pragma unroll
            for (int reg = 0; reg < 4; ++reg) {
                int l = sp*16 + g*4 + reg;
                if (l < LL) {
                    float z0 = oacc[0][reg] + bdv[0] + xp[reg];
                    float z1 = oacc[1][reg] + bdv[1] + xp[4 + reg];
                    float z2 = oacc[2][reg] + bdv[2] + xp[8 + reg];
                    float z3 = oacc[3][reg] + bdv[3] + xp[12 + reg];
                    float s = z0 + z1 + z2 + z3;
                    s += __shfl_xor(s, 1); s += __shfl_xor(s, 2);
                    s += __shfl_xor(s, 4); s += __shfl_xor(s, 8);
                    float mu = s * (1.0f/64.0f);
                    float c0 = z0 - mu, c1 = z1 - mu, c2 = z2 - mu, c3 = z3 - mu;
                    float vs = c0*c0 + c1*c1 + c2*c2 + c3*c3;
                    vs += __shfl_xor(vs, 1); vs += __shfl_xor(vs, 2);
                    vs += __shfl_xor(vs, 4); vs += __shfl_xor(vs, 8);
                    float rstd = rsqrtf(vs * (1.0f/64.0f) + 1e-12f);
                    float* op = out + ((size_t)b*LL + l)*64 + fr;
                    op[0]  = fmaf(gv[0]*rstd, c0, bev[0]);
                    op[16] = fmaf(gv[1]*rstd, c1, bev[1]);
                    op[32] = fmaf(gv[2]*rstd, c2, bev[2]);
                    op[48] = fmaf(gv[3]*rstd, c3, bev[3]);
                }
            }
        }
    }
    #undef LK_TILE
}

// ---------------------------------------------------------------------------
extern "C" void kernel_launch(void* const* d_in, const int* in_sizes, int n_in,
                              void* d_out, int out_size, void* d_ws, size_t ws_size,
                              hipStream_t stream) {
    const float* x     = (const float*)d_in[0];
    const float* mask  = (const float*)d_in[1];
    const int*   ids   = (const int*)  d_in[2];
    const float* C     = (const float*)d_in[3];
    const float* Wq    = (const float*)d_in[4];
    const float* bq    = (const float*)d_in[5];
    const float* Wv    = (const float*)d_in[6];
    const float* bv    = (const float*)d_in[7];
    const float* Wd    = (const float*)d_in[8];
    const float* bd    = (const float*)d_in[9];
    const float* gamma = (const float*)d_in[10];
    const float* beta  = (const float*)d_in[11];
    float* out = (float*)d_out;

    unsigned short* Vb = (unsigned short*)d_ws;   // workspace (unused)

    mega_kernel<<<NB, 1024, LDS_TOTAL, stream>>>(x, mask, ids, C, Wq, bq, Wv, bv,
                                                 Wd, bd, gamma, beta, Vb, out);
}